// Round 3
// baseline (509.789 us; speedup 1.0000x reference)
//
#include <hip/hip_runtime.h>
#include <math.h>

// SGC 2-layer: out = A_hat * elu(A_hat * X * W1 + b1) * W2 + b2
// A_hat = D^-1/2 A D^-1/2 (in-degree based, clip(deg,1))
// R2: CSR build + gather aggregation (no float atomics).
// R3: unroll-4 edge loops in both gathers (more rows in flight per wave);
//     nontemporal loads for the streamed-once esrc array.

#define DIN  128
#define DHID 128
#define DOUT 40

__device__ __forceinline__ float elu_f(float x) {
    return x > 0.0f ? x : (expf(x) - 1.0f);
}

// ---------------- CSR build ----------------

__global__ void degi_kernel(const int* __restrict__ dst, int E, int* __restrict__ deg) {
    int stride = gridDim.x * blockDim.x;
    for (int i = blockIdx.x * blockDim.x + threadIdx.x; i < E; i += stride)
        atomicAdd(&deg[dst[i]], 1);
}

__global__ void norm_from_deg(const int* __restrict__ deg, float* __restrict__ norm, int N) {
    int stride = gridDim.x * blockDim.x;
    for (int i = blockIdx.x * blockDim.x + threadIdx.x; i < N; i += stride)
        norm[i] = rsqrtf(fmaxf((float)deg[i], 1.0f));
}

__global__ void scan_partial(const int* __restrict__ deg, int N, int* __restrict__ bsum) {
    __shared__ int sd[256];
    int i = blockIdx.x * 256 + threadIdx.x;
    sd[threadIdx.x] = (i < N) ? deg[i] : 0;
    __syncthreads();
    for (int s = 128; s > 0; s >>= 1) {
        if (threadIdx.x < s) sd[threadIdx.x] += sd[threadIdx.x + s];
        __syncthreads();
    }
    if (threadIdx.x == 0) bsum[blockIdx.x] = sd[0];
}

__global__ void scan_bsum(int* __restrict__ bsum, int nb) {
    if (blockIdx.x == 0 && threadIdx.x == 0) {
        int acc = 0;
        for (int b = 0; b < nb; ++b) { int v = bsum[b]; bsum[b] = acc; acc += v; }
    }
}

__global__ void scan_final(const int* __restrict__ deg, int N, int E,
                           const int* __restrict__ bsum, int* __restrict__ rowptr) {
    __shared__ int sd[256];
    int tid = threadIdx.x;
    int i = blockIdx.x * 256 + tid;
    int v = (i < N) ? deg[i] : 0;
    sd[tid] = v;
    __syncthreads();
    for (int off = 1; off < 256; off <<= 1) {
        int t = (tid >= off) ? sd[tid - off] : 0;
        __syncthreads();
        sd[tid] += t;
        __syncthreads();
    }
    if (i < N) rowptr[i] = bsum[blockIdx.x] + sd[tid] - v;
    if (i == 0) rowptr[N] = E;
}

__global__ void fill_kernel(const int* __restrict__ src, const int* __restrict__ dst,
                            const int* __restrict__ rowptr, int* __restrict__ cursor,
                            int* __restrict__ esrc, int E) {
    int stride = gridDim.x * blockDim.x;
    for (int e = blockIdx.x * blockDim.x + threadIdx.x; e < E; e += stride) {
        int d = dst[e];
        int pos = rowptr[d] + atomicAdd(&cursor[d], 1);
        esrc[pos] = src[e];
    }
}

// ---------------- gather aggregation ----------------

// agg[n] = sum_j feat[esrc[j]] * norm[esrc[j]] ; 32 lanes per node, float4/lane.
__global__ void gather1_kernel(const float* __restrict__ feat, const float* __restrict__ norm,
                               const int* __restrict__ rowptr, const int* __restrict__ esrc,
                               float* __restrict__ agg, int N) {
    int lane = threadIdx.x & 31;
    long g = ((long)blockIdx.x * blockDim.x + threadIdx.x) >> 5;
    long gstride = ((long)gridDim.x * blockDim.x) >> 5;
    const float4* f4 = reinterpret_cast<const float4*>(feat);
    for (long n = g; n < N; n += gstride) {
        int beg = rowptr[n], end = rowptr[n + 1];
        float4 acc = make_float4(0.f, 0.f, 0.f, 0.f);
        int j = beg;
        for (; j + 3 < end; j += 4) {
            int s0 = __builtin_nontemporal_load(&esrc[j]);
            int s1 = __builtin_nontemporal_load(&esrc[j + 1]);
            int s2 = __builtin_nontemporal_load(&esrc[j + 2]);
            int s3 = __builtin_nontemporal_load(&esrc[j + 3]);
            float n0 = norm[s0], n1 = norm[s1], n2 = norm[s2], n3 = norm[s3];
            float4 v0 = f4[(long)s0 * 32 + lane];
            float4 v1 = f4[(long)s1 * 32 + lane];
            float4 v2 = f4[(long)s2 * 32 + lane];
            float4 v3 = f4[(long)s3 * 32 + lane];
            acc.x = fmaf(v0.x, n0, acc.x); acc.y = fmaf(v0.y, n0, acc.y);
            acc.z = fmaf(v0.z, n0, acc.z); acc.w = fmaf(v0.w, n0, acc.w);
            acc.x = fmaf(v1.x, n1, acc.x); acc.y = fmaf(v1.y, n1, acc.y);
            acc.z = fmaf(v1.z, n1, acc.z); acc.w = fmaf(v1.w, n1, acc.w);
            acc.x = fmaf(v2.x, n2, acc.x); acc.y = fmaf(v2.y, n2, acc.y);
            acc.z = fmaf(v2.z, n2, acc.z); acc.w = fmaf(v2.w, n2, acc.w);
            acc.x = fmaf(v3.x, n3, acc.x); acc.y = fmaf(v3.y, n3, acc.y);
            acc.z = fmaf(v3.z, n3, acc.z); acc.w = fmaf(v3.w, n3, acc.w);
        }
        for (; j < end; ++j) {
            int s0 = __builtin_nontemporal_load(&esrc[j]);
            float n0 = norm[s0];
            float4 v0 = f4[(long)s0 * 32 + lane];
            acc.x = fmaf(v0.x, n0, acc.x); acc.y = fmaf(v0.y, n0, acc.y);
            acc.z = fmaf(v0.z, n0, acc.z); acc.w = fmaf(v0.w, n0, acc.w);
        }
        reinterpret_cast<float4*>(agg)[n * 32 + lane] = acc;
    }
}

// out[n] = norm[n] * sum_j z[esrc[j]] + b2 ; 16 lanes per node, 10 active.
__global__ void gather2_kernel(const float* __restrict__ z, const int* __restrict__ rowptr,
                               const int* __restrict__ esrc, const float* __restrict__ norm,
                               const float* __restrict__ b2, float* __restrict__ out, int N) {
    int lane = threadIdx.x & 15;
    long g = ((long)blockIdx.x * blockDim.x + threadIdx.x) >> 4;
    long gstride = ((long)gridDim.x * blockDim.x) >> 4;
    const float4* z4 = reinterpret_cast<const float4*>(z);
    for (long n = g; n < N; n += gstride) {
        if (lane < 10) {
            int beg = rowptr[n], end = rowptr[n + 1];
            float4 acc = make_float4(0.f, 0.f, 0.f, 0.f);
            int j = beg;
            for (; j + 3 < end; j += 4) {
                int s0 = __builtin_nontemporal_load(&esrc[j]);
                int s1 = __builtin_nontemporal_load(&esrc[j + 1]);
                int s2 = __builtin_nontemporal_load(&esrc[j + 2]);
                int s3 = __builtin_nontemporal_load(&esrc[j + 3]);
                float4 v0 = z4[(long)s0 * 10 + lane];
                float4 v1 = z4[(long)s1 * 10 + lane];
                float4 v2 = z4[(long)s2 * 10 + lane];
                float4 v3 = z4[(long)s3 * 10 + lane];
                acc.x += (v0.x + v1.x) + (v2.x + v3.x);
                acc.y += (v0.y + v1.y) + (v2.y + v3.y);
                acc.z += (v0.z + v1.z) + (v2.z + v3.z);
                acc.w += (v0.w + v1.w) + (v2.w + v3.w);
            }
            for (; j < end; ++j) {
                int s0 = __builtin_nontemporal_load(&esrc[j]);
                float4 v0 = z4[(long)s0 * 10 + lane];
                acc.x += v0.x; acc.y += v0.y; acc.z += v0.z; acc.w += v0.w;
            }
            float nm = norm[n];
            float4 bb = reinterpret_cast<const float4*>(b2)[lane];
            float4 o;
            o.x = fmaf(acc.x, nm, bb.x); o.y = fmaf(acc.y, nm, bb.y);
            o.z = fmaf(acc.z, nm, bb.z); o.w = fmaf(acc.w, nm, bb.w);
            reinterpret_cast<float4*>(out)[n * 10 + lane] = o;
        }
    }
}

// ---------------- dense matmuls ----------------

// h[n] = elu( (agg[n]*norm[n]) @ W1 + b1 ), in-place.
__launch_bounds__(256, 2)
__global__ void mm1_kernel(float* __restrict__ xh, const float* __restrict__ W1,
                           const float* __restrict__ b1, const float* __restrict__ norm,
                           int N) {
    __shared__ float Wl[DIN * DHID];   // 64KB
    __shared__ float Xl[32 * DIN];     // 16KB
    for (int i = threadIdx.x; i < DIN * DHID; i += 256) Wl[i] = W1[i];
    int cg = threadIdx.x & 31;
    int rg = threadIdx.x >> 5;
    int c0 = cg * 4;
    for (long r0 = (long)blockIdx.x * 32; r0 < N; r0 += (long)gridDim.x * 32) {
        __syncthreads();
        for (int i = threadIdx.x; i < 32 * (DIN / 4); i += 256) {
            int rr = i >> 5;
            long row = r0 + rr;
            float4 v = make_float4(0.f, 0.f, 0.f, 0.f);
            if (row < N) {
                v = reinterpret_cast<const float4*>(xh)[row * 32 + (i & 31)];
                float nm = norm[row];
                v.x *= nm; v.y *= nm; v.z *= nm; v.w *= nm;
            }
            reinterpret_cast<float4*>(Xl)[i] = v;
        }
        __syncthreads();
        float acc[4][4];
        float bx = b1[c0], by = b1[c0 + 1], bz = b1[c0 + 2], bw = b1[c0 + 3];
        #pragma unroll
        for (int r = 0; r < 4; ++r) { acc[r][0] = bx; acc[r][1] = by; acc[r][2] = bz; acc[r][3] = bw; }
        for (int k = 0; k < DIN; k += 4) {
            float4 w0 = *reinterpret_cast<const float4*>(&Wl[(k + 0) * DHID + c0]);
            float4 w1 = *reinterpret_cast<const float4*>(&Wl[(k + 1) * DHID + c0]);
            float4 w2 = *reinterpret_cast<const float4*>(&Wl[(k + 2) * DHID + c0]);
            float4 w3 = *reinterpret_cast<const float4*>(&Wl[(k + 3) * DHID + c0]);
            #pragma unroll
            for (int r = 0; r < 4; ++r) {
                float4 x = *reinterpret_cast<const float4*>(&Xl[(rg * 4 + r) * DIN + k]);
                acc[r][0] = fmaf(x.x, w0.x, fmaf(x.y, w1.x, fmaf(x.z, w2.x, fmaf(x.w, w3.x, acc[r][0]))));
                acc[r][1] = fmaf(x.x, w0.y, fmaf(x.y, w1.y, fmaf(x.z, w2.y, fmaf(x.w, w3.y, acc[r][1]))));
                acc[r][2] = fmaf(x.x, w0.z, fmaf(x.y, w1.z, fmaf(x.z, w2.z, fmaf(x.w, w3.z, acc[r][2]))));
                acc[r][3] = fmaf(x.x, w0.w, fmaf(x.y, w1.w, fmaf(x.z, w2.w, fmaf(x.w, w3.w, acc[r][3]))));
            }
        }
        #pragma unroll
        for (int r = 0; r < 4; ++r) {
            long row = r0 + rg * 4 + r;
            if (row < N) {
                float4 o;
                o.x = elu_f(acc[r][0]); o.y = elu_f(acc[r][1]);
                o.z = elu_f(acc[r][2]); o.w = elu_f(acc[r][3]);
                *reinterpret_cast<float4*>(&xh[row * DIN + c0]) = o;
            }
        }
    }
}

// z[n] = norm[n] * (h[n] @ W2)
__launch_bounds__(256, 2)
__global__ void mm2_kernel(const float* __restrict__ h, const float* __restrict__ W2,
                           const float* __restrict__ norm, float* __restrict__ z, int N) {
    __shared__ float Wl[DHID * DOUT];
    __shared__ float Xl[64 * DIN];
    for (int i = threadIdx.x; i < DHID * DOUT; i += 256) Wl[i] = W2[i];
    int cg = threadIdx.x & 15;
    int rg = threadIdx.x >> 4;
    int c0 = cg * 4;
    for (long r0 = (long)blockIdx.x * 64; r0 < N; r0 += (long)gridDim.x * 64) {
        __syncthreads();
        for (int i = threadIdx.x; i < 64 * (DIN / 4); i += 256) {
            int rr = i >> 5;
            long row = r0 + rr;
            float4 v = make_float4(0.f, 0.f, 0.f, 0.f);
            if (row < N) v = reinterpret_cast<const float4*>(h)[row * 32 + (i & 31)];
            reinterpret_cast<float4*>(Xl)[i] = v;
        }
        __syncthreads();
        if (c0 < DOUT) {
            float acc[4][4];
            #pragma unroll
            for (int r = 0; r < 4; ++r) { acc[r][0] = 0.f; acc[r][1] = 0.f; acc[r][2] = 0.f; acc[r][3] = 0.f; }
            for (int k = 0; k < DHID; k += 4) {
                float4 w0 = *reinterpret_cast<const float4*>(&Wl[(k + 0) * DOUT + c0]);
                float4 w1 = *reinterpret_cast<const float4*>(&Wl[(k + 1) * DOUT + c0]);
                float4 w2 = *reinterpret_cast<const float4*>(&Wl[(k + 2) * DOUT + c0]);
                float4 w3 = *reinterpret_cast<const float4*>(&Wl[(k + 3) * DOUT + c0]);
                #pragma unroll
                for (int r = 0; r < 4; ++r) {
                    float4 x = *reinterpret_cast<const float4*>(&Xl[(rg * 4 + r) * DIN + k]);
                    acc[r][0] = fmaf(x.x, w0.x, fmaf(x.y, w1.x, fmaf(x.z, w2.x, fmaf(x.w, w3.x, acc[r][0]))));
                    acc[r][1] = fmaf(x.x, w0.y, fmaf(x.y, w1.y, fmaf(x.z, w2.y, fmaf(x.w, w3.y, acc[r][1]))));
                    acc[r][2] = fmaf(x.x, w0.z, fmaf(x.y, w1.z, fmaf(x.z, w2.z, fmaf(x.w, w3.z, acc[r][2]))));
                    acc[r][3] = fmaf(x.x, w0.w, fmaf(x.y, w1.w, fmaf(x.z, w2.w, fmaf(x.w, w3.w, acc[r][3]))));
                }
            }
            #pragma unroll
            for (int r = 0; r < 4; ++r) {
                long row = r0 + rg * 4 + r;
                if (row < N) {
                    float nm = norm[row];
                    float4 o;
                    o.x = acc[r][0] * nm; o.y = acc[r][1] * nm;
                    o.z = acc[r][2] * nm; o.w = acc[r][3] * nm;
                    *reinterpret_cast<float4*>(&z[row * DOUT + c0]) = o;
                }
            }
        }
    }
}

// ---------------- fallback (atomic path) ----------------

__global__ void scatter1_kernel(const float* __restrict__ feat, const int* __restrict__ src,
                                const int* __restrict__ dst, const float* __restrict__ norm,
                                float* __restrict__ agg, int E) {
    long T = (long)blockIdx.x * blockDim.x + threadIdx.x;
    int l4 = (int)(T & 31);
    long e = T >> 5;
    long estride = ((long)gridDim.x * blockDim.x) >> 5;
    for (; e < E; e += estride) {
        int s = src[e], d = dst[e];
        float ns = norm[s];
        float4 v = reinterpret_cast<const float4*>(feat)[(long)s * 32 + l4];
        float* o = agg + (long)d * DIN + l4 * 4;
        atomicAdd(o + 0, v.x * ns);
        atomicAdd(o + 1, v.y * ns);
        atomicAdd(o + 2, v.z * ns);
        atomicAdd(o + 3, v.w * ns);
    }
}

__global__ void scatter2_kernel(const float* __restrict__ z, const int* __restrict__ src,
                                const int* __restrict__ dst, float* __restrict__ out, int E) {
    long T = (long)blockIdx.x * blockDim.x + threadIdx.x;
    int l = (int)(T & 15);
    long e = T >> 4;
    long estride = ((long)gridDim.x * blockDim.x) >> 4;
    for (; e < E; e += estride) {
        if (l < 10) {
            int s = src[e], d = dst[e];
            float4 v = reinterpret_cast<const float4*>(z)[(long)s * 10 + l];
            float* o = out + (long)d * DOUT + l * 4;
            atomicAdd(o + 0, v.x);
            atomicAdd(o + 1, v.y);
            atomicAdd(o + 2, v.z);
            atomicAdd(o + 3, v.w);
        }
    }
}

__global__ void final_kernel(float* __restrict__ out, const float* __restrict__ norm,
                             const float* __restrict__ b2, int N) {
    long total = (long)N * DOUT;
    long stride = (long)gridDim.x * blockDim.x;
    for (long i = (long)blockIdx.x * blockDim.x + threadIdx.x; i < total; i += stride) {
        int n = (int)(i / DOUT), d = (int)(i % DOUT);
        out[i] = fmaf(out[i], norm[n], b2[d]);
    }
}

// ---------------- launch ----------------

static inline size_t al4k(size_t x) { return (x + 4095) & ~(size_t)4095; }

extern "C" void kernel_launch(void* const* d_in, const int* in_sizes, int n_in,
                              void* d_out, int out_size, void* d_ws, size_t ws_size,
                              hipStream_t stream) {
    const float* feat = (const float*)d_in[0];
    const int*   src  = (const int*)d_in[1];
    const int*   dst  = (const int*)d_in[2];
    const float* W1   = (const float*)d_in[3];
    const float* b1   = (const float*)d_in[4];
    const float* W2   = (const float*)d_in[5];
    const float* b2   = (const float*)d_in[6];
    int N = in_sizes[0] / DIN;
    int E = in_sizes[1];
    float* out = (float*)d_out;
    char* ws = (char*)d_ws;

    int nb = (N + 255) / 256;

    size_t o_norm   = 0;
    size_t o_degi   = o_norm   + al4k((size_t)N * 4);
    size_t o_cursor = o_degi   + al4k((size_t)N * 4);
    size_t o_rowptr = o_cursor + al4k((size_t)N * 4);
    size_t o_bsum   = o_rowptr + al4k(((size_t)N + 1) * 4);
    size_t o_esrc   = o_bsum   + al4k((size_t)nb * 4);
    size_t o_agg    = o_esrc   + al4k((size_t)E * 4);
    size_t o_z      = o_agg    + al4k((size_t)N * DIN * 4);
    size_t need     = o_z      + al4k((size_t)N * DOUT * 4);

    if (ws_size >= need) {
        float* norm   = (float*)(ws + o_norm);
        int*   degi   = (int*)(ws + o_degi);
        int*   cursor = (int*)(ws + o_cursor);
        int*   rowptr = (int*)(ws + o_rowptr);
        int*   bsum   = (int*)(ws + o_bsum);
        int*   esrc   = (int*)(ws + o_esrc);
        float* agg    = (float*)(ws + o_agg);
        float* z      = (float*)(ws + o_z);

        hipMemsetAsync(degi, 0, (size_t)N * 4, stream);
        hipMemsetAsync(cursor, 0, (size_t)N * 4, stream);

        degi_kernel<<<2048, 256, 0, stream>>>(dst, E, degi);
        scan_partial<<<nb, 256, 0, stream>>>(degi, N, bsum);
        scan_bsum<<<1, 1, 0, stream>>>(bsum, nb);
        scan_final<<<nb, 256, 0, stream>>>(degi, N, E, bsum, rowptr);
        norm_from_deg<<<(N + 255) / 256, 256, 0, stream>>>(degi, norm, N);
        fill_kernel<<<2048, 256, 0, stream>>>(src, dst, rowptr, cursor, esrc, E);

        gather1_kernel<<<(N * 32 + 255) / 256, 256, 0, stream>>>(feat, norm, rowptr, esrc, agg, N);
        mm1_kernel<<<(N + 31) / 32, 256, 0, stream>>>(agg, W1, b1, norm, N);
        mm2_kernel<<<(N + 63) / 64, 256, 0, stream>>>(agg, W2, norm, z, N);
        gather2_kernel<<<(N * 16 + 255) / 256, 256, 0, stream>>>(z, rowptr, esrc, norm, b2, out, N);
    } else {
        size_t f_norm = 0;
        size_t f_agg  = f_norm + al4k((size_t)N * 4);
        size_t f_z    = f_agg  + al4k((size_t)N * DIN * 4);
        float* norm = (float*)(ws + f_norm);
        float* agg  = (float*)(ws + f_agg);
        float* z    = (float*)(ws + f_z);
        int*   degi = (int*)(ws + f_norm);

        hipMemsetAsync(degi, 0, (size_t)N * 4, stream);
        hipMemsetAsync(agg, 0, (size_t)N * DIN * 4, stream);
        hipMemsetAsync(d_out, 0, (size_t)N * DOUT * 4, stream);

        degi_kernel<<<1024, 256, 0, stream>>>(dst, E, degi);
        norm_from_deg<<<(N + 255) / 256, 256, 0, stream>>>(degi, (float*)degi, N);
        scatter1_kernel<<<4096, 256, 0, stream>>>(feat, src, dst, norm, agg, E);
        mm1_kernel<<<(N + 31) / 32, 256, 0, stream>>>(agg, W1, b1, norm, N);
        mm2_kernel<<<(N + 63) / 64, 256, 0, stream>>>(agg, W2, norm, z, N);
        scatter2_kernel<<<4096, 256, 0, stream>>>(z, src, dst, out, E);
        final_kernel<<<4096, 256, 0, stream>>>(out, norm, b2, N);
    }
}

// Round 4
// 348.562 us; speedup vs baseline: 1.4625x; 1.4625x over previous
//
#include <hip/hip_runtime.h>
#include <math.h>

// SGC 2-layer: out = A_hat * elu(A_hat * X * W1 + b1) * W2 + b2
// A_hat = D^-1/2 A D^-1/2 (in-degree based, clip(deg,1))
// R2: CSR build + gather aggregation (no float atomics).
// R3: unroll-4 gathers -> REGRESSED (latency not the limiter); reverted.
// R4: CSR build via two-level counting sort (bucket by dst>>9, then per-bucket
//     LDS counting sort). Kills fill_kernel's 107MB random write traffic and
//     2x 1.6M global atomics. Bucket buffer aliases agg.

#define DIN  128
#define DHID 128
#define DOUT 40
#define BSHIFT 9
#define BNODES 512   // 1 << BSHIFT

__device__ __forceinline__ float elu_f(float x) {
    return x > 0.0f ? x : (expf(x) - 1.0f);
}

// ---------------- CSR build (two-level counting sort) ----------------

// pass1: bucket edges by dst>>BSHIFT into bbuf, per-WG LDS histogram + range
// reservation; writes are contiguous runs per (WG,bucket).
__global__ void pass1_bucket(const int* __restrict__ src, const int* __restrict__ dst,
                             int E, int NB, int cap,
                             int* __restrict__ bcur, int2* __restrict__ bbuf) {
    __shared__ int cnt[256];
    __shared__ int wcur[256];
    const int CHUNK = 8192;
    for (long base = (long)blockIdx.x * CHUNK; base < E; base += (long)gridDim.x * CHUNK) {
        int n = min(CHUNK, (int)(E - base));
        if (threadIdx.x < 256) cnt[threadIdx.x] = 0;
        __syncthreads();
        for (int i = threadIdx.x; i < n; i += blockDim.x) {
            int b = dst[base + i] >> BSHIFT;
            atomicAdd(&cnt[b], 1);
        }
        __syncthreads();
        if (threadIdx.x < NB) {
            int c = cnt[threadIdx.x];
            wcur[threadIdx.x] = (c > 0) ? atomicAdd(&bcur[threadIdx.x], c) : 0;
        }
        __syncthreads();
        for (int i = threadIdx.x; i < n; i += blockDim.x) {
            int s = src[base + i];
            int d = dst[base + i];
            int b = d >> BSHIFT;
            int slot = atomicAdd(&wcur[b], 1);
            if (slot < cap) bbuf[(long)b * cap + slot] = make_int2(s, d);
        }
        __syncthreads();
    }
}

// exclusive prefix over NB bucket counts (NB ~ 196, trivial)
__global__ void bucket_scan(const int* __restrict__ bcur, int* __restrict__ bbase, int NB) {
    if (blockIdx.x == 0 && threadIdx.x == 0) {
        int run = 0;
        for (int b = 0; b < NB; ++b) { bbase[b] = run; run += bcur[b]; }
        bbase[NB] = run;
    }
}

// pass2: per-bucket LDS counting sort -> deg, rowptr, esrc (bucket-contiguous writes)
__global__ void pass2_sort(const int2* __restrict__ bbuf, const int* __restrict__ bcur,
                           const int* __restrict__ bbase, int N, int NB, int cap,
                           int* __restrict__ deg, int* __restrict__ rowptr,
                           int* __restrict__ esrc) {
    __shared__ int cnt[BNODES];
    int b = blockIdx.x;
    int n_b = min(bcur[b], cap);
    int gbase = bbase[b];
    int dbase = b << BSHIFT;
    const int2* eb = bbuf + (long)b * cap;
    for (int i = threadIdx.x; i < BNODES; i += blockDim.x) cnt[i] = 0;
    __syncthreads();
    for (int i = threadIdx.x; i < n_b; i += blockDim.x)
        atomicAdd(&cnt[eb[i].y - dbase], 1);
    __syncthreads();
    for (int i = threadIdx.x; i < BNODES; i += blockDim.x) {
        int d = dbase + i;
        if (d < N) deg[d] = cnt[i];
    }
    __syncthreads();
    if (threadIdx.x == 0) {
        int run = 0;
        #pragma unroll 4
        for (int i = 0; i < BNODES; ++i) { int c = cnt[i]; cnt[i] = run; run += c; }
    }
    __syncthreads();
    for (int i = threadIdx.x; i < BNODES; i += blockDim.x) {
        int d = dbase + i;
        if (d < N) rowptr[d] = gbase + cnt[i];
    }
    if (b == NB - 1 && threadIdx.x == 0) rowptr[N] = bbase[NB];
    __syncthreads();
    for (int i = threadIdx.x; i < n_b; i += blockDim.x) {
        int2 e = eb[i];
        int slot = atomicAdd(&cnt[e.y - dbase], 1);
        esrc[gbase + slot] = e.x;
    }
}

__global__ void norm_from_deg(const int* __restrict__ deg, float* __restrict__ norm, int N) {
    int stride = gridDim.x * blockDim.x;
    for (int i = blockIdx.x * blockDim.x + threadIdx.x; i < N; i += stride)
        norm[i] = rsqrtf(fmaxf((float)deg[i], 1.0f));
}

// fallback-path degree count
__global__ void degi_kernel(const int* __restrict__ dst, int E, int* __restrict__ deg) {
    int stride = gridDim.x * blockDim.x;
    for (int i = blockIdx.x * blockDim.x + threadIdx.x; i < E; i += stride)
        atomicAdd(&deg[dst[i]], 1);
}

// ---------------- gather aggregation (R2 form) ----------------

// agg[n] = sum_j feat[esrc[j]] * norm[esrc[j]] ; 32 lanes per node, float4/lane.
__global__ void gather1_kernel(const float* __restrict__ feat, const float* __restrict__ norm,
                               const int* __restrict__ rowptr, const int* __restrict__ esrc,
                               float* __restrict__ agg, int N) {
    int lane = threadIdx.x & 31;
    long g = ((long)blockIdx.x * blockDim.x + threadIdx.x) >> 5;
    long gstride = ((long)gridDim.x * blockDim.x) >> 5;
    const float4* f4 = reinterpret_cast<const float4*>(feat);
    for (long n = g; n < N; n += gstride) {
        int beg = rowptr[n], end = rowptr[n + 1];
        float4 acc = make_float4(0.f, 0.f, 0.f, 0.f);
        int j = beg;
        for (; j + 1 < end; j += 2) {
            int s0 = esrc[j], s1 = esrc[j + 1];
            float n0 = norm[s0], n1 = norm[s1];
            float4 v0 = f4[(long)s0 * 32 + lane];
            float4 v1 = f4[(long)s1 * 32 + lane];
            acc.x = fmaf(v0.x, n0, acc.x); acc.y = fmaf(v0.y, n0, acc.y);
            acc.z = fmaf(v0.z, n0, acc.z); acc.w = fmaf(v0.w, n0, acc.w);
            acc.x = fmaf(v1.x, n1, acc.x); acc.y = fmaf(v1.y, n1, acc.y);
            acc.z = fmaf(v1.z, n1, acc.z); acc.w = fmaf(v1.w, n1, acc.w);
        }
        if (j < end) {
            int s0 = esrc[j];
            float n0 = norm[s0];
            float4 v0 = f4[(long)s0 * 32 + lane];
            acc.x = fmaf(v0.x, n0, acc.x); acc.y = fmaf(v0.y, n0, acc.y);
            acc.z = fmaf(v0.z, n0, acc.z); acc.w = fmaf(v0.w, n0, acc.w);
        }
        reinterpret_cast<float4*>(agg)[n * 32 + lane] = acc;
    }
}

// out[n] = norm[n] * sum_j z[esrc[j]] + b2 ; 16 lanes per node, 10 active.
__global__ void gather2_kernel(const float* __restrict__ z, const int* __restrict__ rowptr,
                               const int* __restrict__ esrc, const float* __restrict__ norm,
                               const float* __restrict__ b2, float* __restrict__ out, int N) {
    int lane = threadIdx.x & 15;
    long g = ((long)blockIdx.x * blockDim.x + threadIdx.x) >> 4;
    long gstride = ((long)gridDim.x * blockDim.x) >> 4;
    const float4* z4 = reinterpret_cast<const float4*>(z);
    for (long n = g; n < N; n += gstride) {
        if (lane < 10) {
            int beg = rowptr[n], end = rowptr[n + 1];
            float4 acc = make_float4(0.f, 0.f, 0.f, 0.f);
            int j = beg;
            for (; j + 1 < end; j += 2) {
                int s0 = esrc[j], s1 = esrc[j + 1];
                float4 v0 = z4[(long)s0 * 10 + lane];
                float4 v1 = z4[(long)s1 * 10 + lane];
                acc.x += v0.x + v1.x; acc.y += v0.y + v1.y;
                acc.z += v0.z + v1.z; acc.w += v0.w + v1.w;
            }
            if (j < end) {
                int s0 = esrc[j];
                float4 v0 = z4[(long)s0 * 10 + lane];
                acc.x += v0.x; acc.y += v0.y; acc.z += v0.z; acc.w += v0.w;
            }
            float nm = norm[n];
            float4 bb = reinterpret_cast<const float4*>(b2)[lane];
            float4 o;
            o.x = fmaf(acc.x, nm, bb.x); o.y = fmaf(acc.y, nm, bb.y);
            o.z = fmaf(acc.z, nm, bb.z); o.w = fmaf(acc.w, nm, bb.w);
            reinterpret_cast<float4*>(out)[n * 10 + lane] = o;
        }
    }
}

// ---------------- dense matmuls ----------------

// h[n] = elu( (agg[n]*norm[n]) @ W1 + b1 ), in-place.
__launch_bounds__(256, 2)
__global__ void mm1_kernel(float* __restrict__ xh, const float* __restrict__ W1,
                           const float* __restrict__ b1, const float* __restrict__ norm,
                           int N) {
    __shared__ float Wl[DIN * DHID];   // 64KB
    __shared__ float Xl[32 * DIN];     // 16KB
    for (int i = threadIdx.x; i < DIN * DHID; i += 256) Wl[i] = W1[i];
    int cg = threadIdx.x & 31;
    int rg = threadIdx.x >> 5;
    int c0 = cg * 4;
    for (long r0 = (long)blockIdx.x * 32; r0 < N; r0 += (long)gridDim.x * 32) {
        __syncthreads();
        for (int i = threadIdx.x; i < 32 * (DIN / 4); i += 256) {
            int rr = i >> 5;
            long row = r0 + rr;
            float4 v = make_float4(0.f, 0.f, 0.f, 0.f);
            if (row < N) {
                v = reinterpret_cast<const float4*>(xh)[row * 32 + (i & 31)];
                float nm = norm[row];
                v.x *= nm; v.y *= nm; v.z *= nm; v.w *= nm;
            }
            reinterpret_cast<float4*>(Xl)[i] = v;
        }
        __syncthreads();
        float acc[4][4];
        float bx = b1[c0], by = b1[c0 + 1], bz = b1[c0 + 2], bw = b1[c0 + 3];
        #pragma unroll
        for (int r = 0; r < 4; ++r) { acc[r][0] = bx; acc[r][1] = by; acc[r][2] = bz; acc[r][3] = bw; }
        for (int k = 0; k < DIN; k += 4) {
            float4 w0 = *reinterpret_cast<const float4*>(&Wl[(k + 0) * DHID + c0]);
            float4 w1 = *reinterpret_cast<const float4*>(&Wl[(k + 1) * DHID + c0]);
            float4 w2 = *reinterpret_cast<const float4*>(&Wl[(k + 2) * DHID + c0]);
            float4 w3 = *reinterpret_cast<const float4*>(&Wl[(k + 3) * DHID + c0]);
            #pragma unroll
            for (int r = 0; r < 4; ++r) {
                float4 x = *reinterpret_cast<const float4*>(&Xl[(rg * 4 + r) * DIN + k]);
                acc[r][0] = fmaf(x.x, w0.x, fmaf(x.y, w1.x, fmaf(x.z, w2.x, fmaf(x.w, w3.x, acc[r][0]))));
                acc[r][1] = fmaf(x.x, w0.y, fmaf(x.y, w1.y, fmaf(x.z, w2.y, fmaf(x.w, w3.y, acc[r][1]))));
                acc[r][2] = fmaf(x.x, w0.z, fmaf(x.y, w1.z, fmaf(x.z, w2.z, fmaf(x.w, w3.z, acc[r][2]))));
                acc[r][3] = fmaf(x.x, w0.w, fmaf(x.y, w1.w, fmaf(x.z, w2.w, fmaf(x.w, w3.w, acc[r][3]))));
            }
        }
        #pragma unroll
        for (int r = 0; r < 4; ++r) {
            long row = r0 + rg * 4 + r;
            if (row < N) {
                float4 o;
                o.x = elu_f(acc[r][0]); o.y = elu_f(acc[r][1]);
                o.z = elu_f(acc[r][2]); o.w = elu_f(acc[r][3]);
                *reinterpret_cast<float4*>(&xh[row * DIN + c0]) = o;
            }
        }
    }
}

// z[n] = norm[n] * (h[n] @ W2)
__launch_bounds__(256, 2)
__global__ void mm2_kernel(const float* __restrict__ h, const float* __restrict__ W2,
                           const float* __restrict__ norm, float* __restrict__ z, int N) {
    __shared__ float Wl[DHID * DOUT];
    __shared__ float Xl[64 * DIN];
    for (int i = threadIdx.x; i < DHID * DOUT; i += 256) Wl[i] = W2[i];
    int cg = threadIdx.x & 15;
    int rg = threadIdx.x >> 4;
    int c0 = cg * 4;
    for (long r0 = (long)blockIdx.x * 64; r0 < N; r0 += (long)gridDim.x * 64) {
        __syncthreads();
        for (int i = threadIdx.x; i < 64 * (DIN / 4); i += 256) {
            int rr = i >> 5;
            long row = r0 + rr;
            float4 v = make_float4(0.f, 0.f, 0.f, 0.f);
            if (row < N) v = reinterpret_cast<const float4*>(h)[row * 32 + (i & 31)];
            reinterpret_cast<float4*>(Xl)[i] = v;
        }
        __syncthreads();
        if (c0 < DOUT) {
            float acc[4][4];
            #pragma unroll
            for (int r = 0; r < 4; ++r) { acc[r][0] = 0.f; acc[r][1] = 0.f; acc[r][2] = 0.f; acc[r][3] = 0.f; }
            for (int k = 0; k < DHID; k += 4) {
                float4 w0 = *reinterpret_cast<const float4*>(&Wl[(k + 0) * DOUT + c0]);
                float4 w1 = *reinterpret_cast<const float4*>(&Wl[(k + 1) * DOUT + c0]);
                float4 w2 = *reinterpret_cast<const float4*>(&Wl[(k + 2) * DOUT + c0]);
                float4 w3 = *reinterpret_cast<const float4*>(&Wl[(k + 3) * DOUT + c0]);
                #pragma unroll
                for (int r = 0; r < 4; ++r) {
                    float4 x = *reinterpret_cast<const float4*>(&Xl[(rg * 4 + r) * DIN + k]);
                    acc[r][0] = fmaf(x.x, w0.x, fmaf(x.y, w1.x, fmaf(x.z, w2.x, fmaf(x.w, w3.x, acc[r][0]))));
                    acc[r][1] = fmaf(x.x, w0.y, fmaf(x.y, w1.y, fmaf(x.z, w2.y, fmaf(x.w, w3.y, acc[r][1]))));
                    acc[r][2] = fmaf(x.x, w0.z, fmaf(x.y, w1.z, fmaf(x.z, w2.z, fmaf(x.w, w3.z, acc[r][2]))));
                    acc[r][3] = fmaf(x.x, w0.w, fmaf(x.y, w1.w, fmaf(x.z, w2.w, fmaf(x.w, w3.w, acc[r][3]))));
                }
            }
            #pragma unroll
            for (int r = 0; r < 4; ++r) {
                long row = r0 + rg * 4 + r;
                if (row < N) {
                    float nm = norm[row];
                    float4 o;
                    o.x = acc[r][0] * nm; o.y = acc[r][1] * nm;
                    o.z = acc[r][2] * nm; o.w = acc[r][3] * nm;
                    *reinterpret_cast<float4*>(&z[row * DOUT + c0]) = o;
                }
            }
        }
    }
}

// ---------------- fallback (atomic path) ----------------

__global__ void scatter1_kernel(const float* __restrict__ feat, const int* __restrict__ src,
                                const int* __restrict__ dst, const float* __restrict__ norm,
                                float* __restrict__ agg, int E) {
    long T = (long)blockIdx.x * blockDim.x + threadIdx.x;
    int l4 = (int)(T & 31);
    long e = T >> 5;
    long estride = ((long)gridDim.x * blockDim.x) >> 5;
    for (; e < E; e += estride) {
        int s = src[e], d = dst[e];
        float ns = norm[s];
        float4 v = reinterpret_cast<const float4*>(feat)[(long)s * 32 + l4];
        float* o = agg + (long)d * DIN + l4 * 4;
        atomicAdd(o + 0, v.x * ns);
        atomicAdd(o + 1, v.y * ns);
        atomicAdd(o + 2, v.z * ns);
        atomicAdd(o + 3, v.w * ns);
    }
}

__global__ void scatter2_kernel(const float* __restrict__ z, const int* __restrict__ src,
                                const int* __restrict__ dst, float* __restrict__ out, int E) {
    long T = (long)blockIdx.x * blockDim.x + threadIdx.x;
    int l = (int)(T & 15);
    long e = T >> 4;
    long estride = ((long)gridDim.x * blockDim.x) >> 4;
    for (; e < E; e += estride) {
        if (l < 10) {
            int s = src[e], d = dst[e];
            float4 v = reinterpret_cast<const float4*>(z)[(long)s * 10 + l];
            float* o = out + (long)d * DOUT + l * 4;
            atomicAdd(o + 0, v.x);
            atomicAdd(o + 1, v.y);
            atomicAdd(o + 2, v.z);
            atomicAdd(o + 3, v.w);
        }
    }
}

__global__ void final_kernel(float* __restrict__ out, const float* __restrict__ norm,
                             const float* __restrict__ b2, int N) {
    long total = (long)N * DOUT;
    long stride = (long)gridDim.x * blockDim.x;
    for (long i = (long)blockIdx.x * blockDim.x + threadIdx.x; i < total; i += stride) {
        int n = (int)(i / DOUT), d = (int)(i % DOUT);
        out[i] = fmaf(out[i], norm[n], b2[d]);
    }
}

// ---------------- launch ----------------

static inline size_t al4k(size_t x) { return (x + 4095) & ~(size_t)4095; }

extern "C" void kernel_launch(void* const* d_in, const int* in_sizes, int n_in,
                              void* d_out, int out_size, void* d_ws, size_t ws_size,
                              hipStream_t stream) {
    const float* feat = (const float*)d_in[0];
    const int*   src  = (const int*)d_in[1];
    const int*   dst  = (const int*)d_in[2];
    const float* W1   = (const float*)d_in[3];
    const float* b1   = (const float*)d_in[4];
    const float* W2   = (const float*)d_in[5];
    const float* b2   = (const float*)d_in[6];
    int N = in_sizes[0] / DIN;
    int E = in_sizes[1];
    float* out = (float*)d_out;
    char* ws = (char*)d_ws;

    int NB = (N + BNODES - 1) >> BSHIFT;
    int cap = ((E / (NB > 0 ? NB : 1)) * 5 / 4 + 256 + 1) & ~1;

    size_t o_norm   = 0;
    size_t o_deg    = o_norm   + al4k((size_t)N * 4);
    size_t o_rowptr = o_deg    + al4k((size_t)N * 4);
    size_t o_bcur   = o_rowptr + al4k(((size_t)N + 1) * 4);
    size_t o_bbase  = o_bcur   + al4k((size_t)(NB + 1) * 4);
    size_t o_esrc   = o_bbase  + al4k((size_t)(NB + 1) * 4);
    size_t o_agg    = o_esrc   + al4k((size_t)E * 4);       // bucketbuf aliases agg
    size_t o_z      = o_agg    + al4k((size_t)N * DIN * 4);
    size_t need     = o_z      + al4k((size_t)N * DOUT * 4);

    bool bb_fits = (size_t)NB * cap * 8 <= (size_t)N * DIN * 4;

    if (ws_size >= need && NB <= 256 && bb_fits) {
        float* norm   = (float*)(ws + o_norm);
        int*   deg    = (int*)(ws + o_deg);
        int*   rowptr = (int*)(ws + o_rowptr);
        int*   bcur   = (int*)(ws + o_bcur);
        int*   bbase  = (int*)(ws + o_bbase);
        int*   esrc   = (int*)(ws + o_esrc);
        float* agg    = (float*)(ws + o_agg);
        int2*  bbuf   = (int2*)(ws + o_agg);
        float* z      = (float*)(ws + o_z);

        hipMemsetAsync(bcur, 0, (size_t)(NB + 1) * 4, stream);

        int p1grid = (E + 8191) / 8192;
        pass1_bucket<<<p1grid, 256, 0, stream>>>(src, dst, E, NB, cap, bcur, bbuf);
        bucket_scan<<<1, 1, 0, stream>>>(bcur, bbase, NB);
        pass2_sort<<<NB, 256, 0, stream>>>(bbuf, bcur, bbase, N, NB, cap, deg, rowptr, esrc);
        norm_from_deg<<<(N + 255) / 256, 256, 0, stream>>>(deg, norm, N);

        gather1_kernel<<<(N * 32 + 255) / 256, 256, 0, stream>>>(feat, norm, rowptr, esrc, agg, N);
        mm1_kernel<<<(N + 31) / 32, 256, 0, stream>>>(agg, W1, b1, norm, N);
        mm2_kernel<<<(N + 63) / 64, 256, 0, stream>>>(agg, W2, norm, z, N);
        gather2_kernel<<<(N * 16 + 255) / 256, 256, 0, stream>>>(z, rowptr, esrc, norm, b2, out, N);
    } else {
        size_t f_norm = 0;
        size_t f_agg  = f_norm + al4k((size_t)N * 4);
        size_t f_z    = f_agg  + al4k((size_t)N * DIN * 4);
        float* norm = (float*)(ws + f_norm);
        float* agg  = (float*)(ws + f_agg);
        float* z    = (float*)(ws + f_z);
        int*   degi = (int*)(ws + f_norm);

        hipMemsetAsync(degi, 0, (size_t)N * 4, stream);
        hipMemsetAsync(agg, 0, (size_t)N * DIN * 4, stream);
        hipMemsetAsync(d_out, 0, (size_t)N * DOUT * 4, stream);

        degi_kernel<<<1024, 256, 0, stream>>>(dst, E, degi);
        norm_from_deg<<<(N + 255) / 256, 256, 0, stream>>>(degi, (float*)degi, N);
        scatter1_kernel<<<4096, 256, 0, stream>>>(feat, src, dst, norm, agg, E);
        mm1_kernel<<<(N + 31) / 32, 256, 0, stream>>>(agg, W1, b1, norm, N);
        mm2_kernel<<<(N + 63) / 64, 256, 0, stream>>>(agg, W2, norm, z, N);
        scatter2_kernel<<<4096, 256, 0, stream>>>(z, src, dst, out, E);
        final_kernel<<<4096, 256, 0, stream>>>(out, norm, b2, N);
    }
}

// Round 5
// 312.358 us; speedup vs baseline: 1.6321x; 1.1159x over previous
//
#include <hip/hip_runtime.h>
#include <hip/hip_fp16.h>
#include <math.h>

// SGC 2-layer: out = A_hat * elu(A_hat * X * W1 + b1) * W2 + b2
// A_hat = D^-1/2 A D^-1/2 (in-degree based, clip(deg,1))
// R2: CSR build + gather aggregation (no float atomics).
// R3: unroll-4 gathers -> REGRESSED (latency not the limiter); reverted.
// R4: CSR via two-level counting sort (bucket dst>>9 then LDS sort). 510->348us.
// R5: fp16 gather operands (y=feat*norm, agg/h, z) -> halve the random-gather
//     bytes/edge that dominate (gather1 FETCH 391MB @ 3.8TB/s effective).
//     Accumulation stays fp32; fp16 eps 2^-11 keeps absmax ~1e-3 (<8.87e-3).

#define DIN  128
#define DHID 128
#define DOUT 40
#define BSHIFT 9
#define BNODES 512   // 1 << BSHIFT

union U8 { uint2 u; __half2 h[2]; };

__device__ __forceinline__ float elu_f(float x) {
    return x > 0.0f ? x : (expf(x) - 1.0f);
}

// ---------------- CSR build (two-level counting sort) ----------------

__global__ void pass1_bucket(const int* __restrict__ src, const int* __restrict__ dst,
                             int E, int NB, int cap,
                             int* __restrict__ bcur, int2* __restrict__ bbuf) {
    __shared__ int cnt[256];
    __shared__ int wcur[256];
    const int CHUNK = 8192;
    for (long base = (long)blockIdx.x * CHUNK; base < E; base += (long)gridDim.x * CHUNK) {
        int n = min(CHUNK, (int)(E - base));
        if (threadIdx.x < 256) cnt[threadIdx.x] = 0;
        __syncthreads();
        for (int i = threadIdx.x; i < n; i += blockDim.x) {
            int b = dst[base + i] >> BSHIFT;
            atomicAdd(&cnt[b], 1);
        }
        __syncthreads();
        if (threadIdx.x < NB) {
            int c = cnt[threadIdx.x];
            wcur[threadIdx.x] = (c > 0) ? atomicAdd(&bcur[threadIdx.x], c) : 0;
        }
        __syncthreads();
        for (int i = threadIdx.x; i < n; i += blockDim.x) {
            int s = src[base + i];
            int d = dst[base + i];
            int b = d >> BSHIFT;
            int slot = atomicAdd(&wcur[b], 1);
            if (slot < cap) bbuf[(long)b * cap + slot] = make_int2(s, d);
        }
        __syncthreads();
    }
}

__global__ void bucket_scan(const int* __restrict__ bcur, int* __restrict__ bbase, int NB) {
    if (blockIdx.x == 0 && threadIdx.x == 0) {
        int run = 0;
        for (int b = 0; b < NB; ++b) { bbase[b] = run; run += bcur[b]; }
        bbase[NB] = run;
    }
}

// per-bucket LDS counting sort -> norm, rowptr, esrc
__global__ void pass2_sort(const int2* __restrict__ bbuf, const int* __restrict__ bcur,
                           const int* __restrict__ bbase, int N, int NB, int cap,
                           float* __restrict__ norm, int* __restrict__ rowptr,
                           int* __restrict__ esrc) {
    __shared__ int cnt[BNODES];
    int b = blockIdx.x;
    int n_b = min(bcur[b], cap);
    int gbase = bbase[b];
    int dbase = b << BSHIFT;
    const int2* eb = bbuf + (long)b * cap;
    for (int i = threadIdx.x; i < BNODES; i += blockDim.x) cnt[i] = 0;
    __syncthreads();
    for (int i = threadIdx.x; i < n_b; i += blockDim.x)
        atomicAdd(&cnt[eb[i].y - dbase], 1);
    __syncthreads();
    for (int i = threadIdx.x; i < BNODES; i += blockDim.x) {
        int d = dbase + i;
        if (d < N) norm[d] = rsqrtf(fmaxf((float)cnt[i], 1.0f));
    }
    __syncthreads();
    if (threadIdx.x == 0) {
        int run = 0;
        #pragma unroll 4
        for (int i = 0; i < BNODES; ++i) { int c = cnt[i]; cnt[i] = run; run += c; }
    }
    __syncthreads();
    for (int i = threadIdx.x; i < BNODES; i += blockDim.x) {
        int d = dbase + i;
        if (d < N) rowptr[d] = gbase + cnt[i];
    }
    if (b == NB - 1 && threadIdx.x == 0) rowptr[N] = bbase[NB];
    __syncthreads();
    for (int i = threadIdx.x; i < n_b; i += blockDim.x) {
        int2 e = eb[i];
        int slot = atomicAdd(&cnt[e.y - dbase], 1);
        esrc[gbase + slot] = e.x;
    }
}

__global__ void norm_from_deg(const int* __restrict__ deg, float* __restrict__ norm, int N) {
    int stride = gridDim.x * blockDim.x;
    for (int i = blockIdx.x * blockDim.x + threadIdx.x; i < N; i += stride)
        norm[i] = rsqrtf(fmaxf((float)deg[i], 1.0f));
}

__global__ void degi_kernel(const int* __restrict__ dst, int E, int* __restrict__ deg) {
    int stride = gridDim.x * blockDim.x;
    for (int i = blockIdx.x * blockDim.x + threadIdx.x; i < E; i += stride)
        atomicAdd(&deg[dst[i]], 1);
}

// ---------------- fp16 staging + gathers ----------------

// y[n][d] = fp16(feat[n][d] * norm[n])
__global__ void yconv_kernel(const float* __restrict__ feat, const float* __restrict__ norm,
                             __half* __restrict__ y, int N) {
    long total = (long)N * 32;   // float4 groups
    long stride = (long)gridDim.x * blockDim.x;
    const float4* f4 = reinterpret_cast<const float4*>(feat);
    uint2* y2 = reinterpret_cast<uint2*>(y);
    for (long i = (long)blockIdx.x * blockDim.x + threadIdx.x; i < total; i += stride) {
        int n = (int)(i >> 5);
        float nm = norm[n];
        float4 v = f4[i];
        U8 o;
        o.h[0] = __floats2half2_rn(v.x * nm, v.y * nm);
        o.h[1] = __floats2half2_rn(v.z * nm, v.w * nm);
        y2[i] = o.u;
    }
}

// aggh[n] = fp16( sum_j y[esrc[j]] ) ; 32 lanes per node, 4 halves/lane.
__global__ void gather1_kernel(const __half* __restrict__ y, const int* __restrict__ rowptr,
                               const int* __restrict__ esrc, __half* __restrict__ aggh, int N) {
    int lane = threadIdx.x & 31;
    long g = ((long)blockIdx.x * blockDim.x + threadIdx.x) >> 5;
    long gstride = ((long)gridDim.x * blockDim.x) >> 5;
    const uint2* y2 = reinterpret_cast<const uint2*>(y);
    uint2* a2 = reinterpret_cast<uint2*>(aggh);
    for (long n = g; n < N; n += gstride) {
        int beg = rowptr[n], end = rowptr[n + 1];
        float a0 = 0.f, a1 = 0.f, a2f = 0.f, a3 = 0.f;
        int j = beg;
        for (; j + 1 < end; j += 2) {
            int s0 = esrc[j], s1 = esrc[j + 1];
            U8 u0, u1;
            u0.u = y2[(long)s0 * 32 + lane];
            u1.u = y2[(long)s1 * 32 + lane];
            float2 p0 = __half22float2(u0.h[0]), p1 = __half22float2(u0.h[1]);
            float2 q0 = __half22float2(u1.h[0]), q1 = __half22float2(u1.h[1]);
            a0 += p0.x + q0.x; a1 += p0.y + q0.y;
            a2f += p1.x + q1.x; a3 += p1.y + q1.y;
        }
        if (j < end) {
            int s0 = esrc[j];
            U8 u0; u0.u = y2[(long)s0 * 32 + lane];
            float2 p0 = __half22float2(u0.h[0]), p1 = __half22float2(u0.h[1]);
            a0 += p0.x; a1 += p0.y; a2f += p1.x; a3 += p1.y;
        }
        U8 o;
        o.h[0] = __floats2half2_rn(a0, a1);
        o.h[1] = __floats2half2_rn(a2f, a3);
        a2[n * 32 + lane] = o.u;
    }
}

// out[n] = norm[n] * sum_j z[esrc[j]] + b2 ; 16 lanes per node, 10 active.
__global__ void gather2_kernel(const __half* __restrict__ z, const int* __restrict__ rowptr,
                               const int* __restrict__ esrc, const float* __restrict__ norm,
                               const float* __restrict__ b2, float* __restrict__ out, int N) {
    int lane = threadIdx.x & 15;
    long g = ((long)blockIdx.x * blockDim.x + threadIdx.x) >> 4;
    long gstride = ((long)gridDim.x * blockDim.x) >> 4;
    const uint2* z2 = reinterpret_cast<const uint2*>(z);
    for (long n = g; n < N; n += gstride) {
        if (lane < 10) {
            int beg = rowptr[n], end = rowptr[n + 1];
            float a0 = 0.f, a1 = 0.f, a2f = 0.f, a3 = 0.f;
            int j = beg;
            for (; j + 1 < end; j += 2) {
                int s0 = esrc[j], s1 = esrc[j + 1];
                U8 u0, u1;
                u0.u = z2[(long)s0 * 10 + lane];
                u1.u = z2[(long)s1 * 10 + lane];
                float2 p0 = __half22float2(u0.h[0]), p1 = __half22float2(u0.h[1]);
                float2 q0 = __half22float2(u1.h[0]), q1 = __half22float2(u1.h[1]);
                a0 += p0.x + q0.x; a1 += p0.y + q0.y;
                a2f += p1.x + q1.x; a3 += p1.y + q1.y;
            }
            if (j < end) {
                int s0 = esrc[j];
                U8 u0; u0.u = z2[(long)s0 * 10 + lane];
                float2 p0 = __half22float2(u0.h[0]), p1 = __half22float2(u0.h[1]);
                a0 += p0.x; a1 += p0.y; a2f += p1.x; a3 += p1.y;
            }
            float nm = norm[n];
            float4 bb = reinterpret_cast<const float4*>(b2)[lane];
            float4 o;
            o.x = fmaf(a0, nm, bb.x); o.y = fmaf(a1, nm, bb.y);
            o.z = fmaf(a2f, nm, bb.z); o.w = fmaf(a3, nm, bb.w);
            reinterpret_cast<float4*>(out)[n * 10 + lane] = o;
        }
    }
}

// ---------------- dense matmuls (fp16 in/out, fp32 math) ----------------

// h[n] = fp16( elu( (aggh[n]*norm[n]) @ W1 + b1 ) ), in-place on aggh.
__launch_bounds__(256, 2)
__global__ void mm1_kernel(__half* __restrict__ xh, const float* __restrict__ W1,
                           const float* __restrict__ b1, const float* __restrict__ norm,
                           int N) {
    __shared__ float Wl[DIN * DHID];   // 64KB
    __shared__ float Xl[32 * DIN];     // 16KB
    for (int i = threadIdx.x; i < DIN * DHID; i += 256) Wl[i] = W1[i];
    int cg = threadIdx.x & 31;
    int rg = threadIdx.x >> 5;
    int c0 = cg * 4;
    for (long r0 = (long)blockIdx.x * 32; r0 < N; r0 += (long)gridDim.x * 32) {
        __syncthreads();
        for (int i = threadIdx.x; i < 32 * 32; i += 256) {
            int rr = i >> 5;
            long row = r0 + rr;
            float4 v = make_float4(0.f, 0.f, 0.f, 0.f);
            if (row < N) {
                U8 u; u.u = reinterpret_cast<const uint2*>(xh)[row * 32 + (i & 31)];
                float2 f0 = __half22float2(u.h[0]), f1 = __half22float2(u.h[1]);
                float nm = norm[row];
                v = make_float4(f0.x * nm, f0.y * nm, f1.x * nm, f1.y * nm);
            }
            reinterpret_cast<float4*>(Xl)[i] = v;
        }
        __syncthreads();
        float acc[4][4];
        float bx = b1[c0], by = b1[c0 + 1], bz = b1[c0 + 2], bw = b1[c0 + 3];
        #pragma unroll
        for (int r = 0; r < 4; ++r) { acc[r][0] = bx; acc[r][1] = by; acc[r][2] = bz; acc[r][3] = bw; }
        for (int k = 0; k < DIN; k += 4) {
            float4 w0 = *reinterpret_cast<const float4*>(&Wl[(k + 0) * DHID + c0]);
            float4 w1 = *reinterpret_cast<const float4*>(&Wl[(k + 1) * DHID + c0]);
            float4 w2 = *reinterpret_cast<const float4*>(&Wl[(k + 2) * DHID + c0]);
            float4 w3 = *reinterpret_cast<const float4*>(&Wl[(k + 3) * DHID + c0]);
            #pragma unroll
            for (int r = 0; r < 4; ++r) {
                float4 x = *reinterpret_cast<const float4*>(&Xl[(rg * 4 + r) * DIN + k]);
                acc[r][0] = fmaf(x.x, w0.x, fmaf(x.y, w1.x, fmaf(x.z, w2.x, fmaf(x.w, w3.x, acc[r][0]))));
                acc[r][1] = fmaf(x.x, w0.y, fmaf(x.y, w1.y, fmaf(x.z, w2.y, fmaf(x.w, w3.y, acc[r][1]))));
                acc[r][2] = fmaf(x.x, w0.z, fmaf(x.y, w1.z, fmaf(x.z, w2.z, fmaf(x.w, w3.z, acc[r][2]))));
                acc[r][3] = fmaf(x.x, w0.w, fmaf(x.y, w1.w, fmaf(x.z, w2.w, fmaf(x.w, w3.w, acc[r][3]))));
            }
        }
        #pragma unroll
        for (int r = 0; r < 4; ++r) {
            long row = r0 + rg * 4 + r;
            if (row < N) {
                U8 o;
                o.h[0] = __floats2half2_rn(elu_f(acc[r][0]), elu_f(acc[r][1]));
                o.h[1] = __floats2half2_rn(elu_f(acc[r][2]), elu_f(acc[r][3]));
                reinterpret_cast<uint2*>(xh)[row * 32 + cg] = o.u;
            }
        }
    }
}

// z[n] = fp16( norm[n] * (h[n] @ W2) )
__launch_bounds__(256, 2)
__global__ void mm2_kernel(const __half* __restrict__ h, const float* __restrict__ W2,
                           const float* __restrict__ norm, __half* __restrict__ z, int N) {
    __shared__ float Wl[DHID * DOUT];
    __shared__ float Xl[64 * DIN];
    for (int i = threadIdx.x; i < DHID * DOUT; i += 256) Wl[i] = W2[i];
    int cg = threadIdx.x & 15;
    int rg = threadIdx.x >> 4;
    int c0 = cg * 4;
    for (long r0 = (long)blockIdx.x * 64; r0 < N; r0 += (long)gridDim.x * 64) {
        __syncthreads();
        for (int i = threadIdx.x; i < 64 * 32; i += 256) {
            int rr = i >> 5;
            long row = r0 + rr;
            float4 v = make_float4(0.f, 0.f, 0.f, 0.f);
            if (row < N) {
                U8 u; u.u = reinterpret_cast<const uint2*>(h)[row * 32 + (i & 31)];
                float2 f0 = __half22float2(u.h[0]), f1 = __half22float2(u.h[1]);
                v = make_float4(f0.x, f0.y, f1.x, f1.y);
            }
            reinterpret_cast<float4*>(Xl)[i] = v;
        }
        __syncthreads();
        if (c0 < DOUT) {
            float acc[4][4];
            #pragma unroll
            for (int r = 0; r < 4; ++r) { acc[r][0] = 0.f; acc[r][1] = 0.f; acc[r][2] = 0.f; acc[r][3] = 0.f; }
            for (int k = 0; k < DHID; k += 4) {
                float4 w0 = *reinterpret_cast<const float4*>(&Wl[(k + 0) * DOUT + c0]);
                float4 w1 = *reinterpret_cast<const float4*>(&Wl[(k + 1) * DOUT + c0]);
                float4 w2 = *reinterpret_cast<const float4*>(&Wl[(k + 2) * DOUT + c0]);
                float4 w3 = *reinterpret_cast<const float4*>(&Wl[(k + 3) * DOUT + c0]);
                #pragma unroll
                for (int r = 0; r < 4; ++r) {
                    float4 x = *reinterpret_cast<const float4*>(&Xl[(rg * 4 + r) * DIN + k]);
                    acc[r][0] = fmaf(x.x, w0.x, fmaf(x.y, w1.x, fmaf(x.z, w2.x, fmaf(x.w, w3.x, acc[r][0]))));
                    acc[r][1] = fmaf(x.x, w0.y, fmaf(x.y, w1.y, fmaf(x.z, w2.y, fmaf(x.w, w3.y, acc[r][1]))));
                    acc[r][2] = fmaf(x.x, w0.z, fmaf(x.y, w1.z, fmaf(x.z, w2.z, fmaf(x.w, w3.z, acc[r][2]))));
                    acc[r][3] = fmaf(x.x, w0.w, fmaf(x.y, w1.w, fmaf(x.z, w2.w, fmaf(x.w, w3.w, acc[r][3]))));
                }
            }
            #pragma unroll
            for (int r = 0; r < 4; ++r) {
                long row = r0 + rg * 4 + r;
                if (row < N) {
                    float nm = norm[row];
                    U8 o;
                    o.h[0] = __floats2half2_rn(acc[r][0] * nm, acc[r][1] * nm);
                    o.h[1] = __floats2half2_rn(acc[r][2] * nm, acc[r][3] * nm);
                    reinterpret_cast<uint2*>(z)[row * 10 + cg] = o.u;
                }
            }
        }
    }
}

// ---------------- fallback (f32 atomic path) ----------------

__global__ void scatter1_kernel(const float* __restrict__ feat, const int* __restrict__ src,
                                const int* __restrict__ dst, const float* __restrict__ norm,
                                float* __restrict__ agg, int E) {
    long T = (long)blockIdx.x * blockDim.x + threadIdx.x;
    int l4 = (int)(T & 31);
    long e = T >> 5;
    long estride = ((long)gridDim.x * blockDim.x) >> 5;
    for (; e < E; e += estride) {
        int s = src[e], d = dst[e];
        float ns = norm[s];
        float4 v = reinterpret_cast<const float4*>(feat)[(long)s * 32 + l4];
        float* o = agg + (long)d * DIN + l4 * 4;
        atomicAdd(o + 0, v.x * ns);
        atomicAdd(o + 1, v.y * ns);
        atomicAdd(o + 2, v.z * ns);
        atomicAdd(o + 3, v.w * ns);
    }
}

__global__ void scatter2_kernel(const float* __restrict__ z, const int* __restrict__ src,
                                const int* __restrict__ dst, float* __restrict__ out, int E) {
    long T = (long)blockIdx.x * blockDim.x + threadIdx.x;
    int l = (int)(T & 15);
    long e = T >> 4;
    long estride = ((long)gridDim.x * blockDim.x) >> 4;
    for (; e < E; e += estride) {
        if (l < 10) {
            int s = src[e], d = dst[e];
            float4 v = reinterpret_cast<const float4*>(z)[(long)s * 10 + l];
            float* o = out + (long)d * DOUT + l * 4;
            atomicAdd(o + 0, v.x);
            atomicAdd(o + 1, v.y);
            atomicAdd(o + 2, v.z);
            atomicAdd(o + 3, v.w);
        }
    }
}

__launch_bounds__(256, 2)
__global__ void mm1f_kernel(float* __restrict__ xh, const float* __restrict__ W1,
                            const float* __restrict__ b1, const float* __restrict__ norm,
                            int N) {
    __shared__ float Wl[DIN * DHID];
    __shared__ float Xl[32 * DIN];
    for (int i = threadIdx.x; i < DIN * DHID; i += 256) Wl[i] = W1[i];
    int cg = threadIdx.x & 31;
    int rg = threadIdx.x >> 5;
    int c0 = cg * 4;
    for (long r0 = (long)blockIdx.x * 32; r0 < N; r0 += (long)gridDim.x * 32) {
        __syncthreads();
        for (int i = threadIdx.x; i < 32 * 32; i += 256) {
            int rr = i >> 5;
            long row = r0 + rr;
            float4 v = make_float4(0.f, 0.f, 0.f, 0.f);
            if (row < N) {
                v = reinterpret_cast<const float4*>(xh)[row * 32 + (i & 31)];
                float nm = norm[row];
                v.x *= nm; v.y *= nm; v.z *= nm; v.w *= nm;
            }
            reinterpret_cast<float4*>(Xl)[i] = v;
        }
        __syncthreads();
        float acc[4][4];
        float bx = b1[c0], by = b1[c0 + 1], bz = b1[c0 + 2], bw = b1[c0 + 3];
        #pragma unroll
        for (int r = 0; r < 4; ++r) { acc[r][0] = bx; acc[r][1] = by; acc[r][2] = bz; acc[r][3] = bw; }
        for (int k = 0; k < DIN; k += 4) {
            float4 w0 = *reinterpret_cast<const float4*>(&Wl[(k + 0) * DHID + c0]);
            float4 w1 = *reinterpret_cast<const float4*>(&Wl[(k + 1) * DHID + c0]);
            float4 w2 = *reinterpret_cast<const float4*>(&Wl[(k + 2) * DHID + c0]);
            float4 w3 = *reinterpret_cast<const float4*>(&Wl[(k + 3) * DHID + c0]);
            #pragma unroll
            for (int r = 0; r < 4; ++r) {
                float4 x = *reinterpret_cast<const float4*>(&Xl[(rg * 4 + r) * DIN + k]);
                acc[r][0] = fmaf(x.x, w0.x, fmaf(x.y, w1.x, fmaf(x.z, w2.x, fmaf(x.w, w3.x, acc[r][0]))));
                acc[r][1] = fmaf(x.x, w0.y, fmaf(x.y, w1.y, fmaf(x.z, w2.y, fmaf(x.w, w3.y, acc[r][1]))));
                acc[r][2] = fmaf(x.x, w0.z, fmaf(x.y, w1.z, fmaf(x.z, w2.z, fmaf(x.w, w3.z, acc[r][2]))));
                acc[r][3] = fmaf(x.x, w0.w, fmaf(x.y, w1.w, fmaf(x.z, w2.w, fmaf(x.w, w3.w, acc[r][3]))));
            }
        }
        #pragma unroll
        for (int r = 0; r < 4; ++r) {
            long row = r0 + rg * 4 + r;
            if (row < N) {
                float4 o;
                o.x = elu_f(acc[r][0]); o.y = elu_f(acc[r][1]);
                o.z = elu_f(acc[r][2]); o.w = elu_f(acc[r][3]);
                *reinterpret_cast<float4*>(&xh[row * DIN + c0]) = o;
            }
        }
    }
}

__launch_bounds__(256, 2)
__global__ void mm2f_kernel(const float* __restrict__ h, const float* __restrict__ W2,
                            const float* __restrict__ norm, float* __restrict__ z, int N) {
    __shared__ float Wl[DHID * DOUT];
    __shared__ float Xl[64 * DIN];
    for (int i = threadIdx.x; i < DHID * DOUT; i += 256) Wl[i] = W2[i];
    int cg = threadIdx.x & 15;
    int rg = threadIdx.x >> 4;
    int c0 = cg * 4;
    for (long r0 = (long)blockIdx.x * 64; r0 < N; r0 += (long)gridDim.x * 64) {
        __syncthreads();
        for (int i = threadIdx.x; i < 64 * 32; i += 256) {
            int rr = i >> 5;
            long row = r0 + rr;
            float4 v = make_float4(0.f, 0.f, 0.f, 0.f);
            if (row < N) v = reinterpret_cast<const float4*>(h)[row * 32 + (i & 31)];
            reinterpret_cast<float4*>(Xl)[i] = v;
        }
        __syncthreads();
        if (c0 < DOUT) {
            float acc[4][4];
            #pragma unroll
            for (int r = 0; r < 4; ++r) { acc[r][0] = 0.f; acc[r][1] = 0.f; acc[r][2] = 0.f; acc[r][3] = 0.f; }
            for (int k = 0; k < DHID; k += 4) {
                float4 w0 = *reinterpret_cast<const float4*>(&Wl[(k + 0) * DOUT + c0]);
                float4 w1 = *reinterpret_cast<const float4*>(&Wl[(k + 1) * DOUT + c0]);
                float4 w2 = *reinterpret_cast<const float4*>(&Wl[(k + 2) * DOUT + c0]);
                float4 w3 = *reinterpret_cast<const float4*>(&Wl[(k + 3) * DOUT + c0]);
                #pragma unroll
                for (int r = 0; r < 4; ++r) {
                    float4 x = *reinterpret_cast<const float4*>(&Xl[(rg * 4 + r) * DIN + k]);
                    acc[r][0] = fmaf(x.x, w0.x, fmaf(x.y, w1.x, fmaf(x.z, w2.x, fmaf(x.w, w3.x, acc[r][0]))));
                    acc[r][1] = fmaf(x.x, w0.y, fmaf(x.y, w1.y, fmaf(x.z, w2.y, fmaf(x.w, w3.y, acc[r][1]))));
                    acc[r][2] = fmaf(x.x, w0.z, fmaf(x.y, w1.z, fmaf(x.z, w2.z, fmaf(x.w, w3.z, acc[r][2]))));
                    acc[r][3] = fmaf(x.x, w0.w, fmaf(x.y, w1.w, fmaf(x.z, w2.w, fmaf(x.w, w3.w, acc[r][3]))));
                }
            }
            #pragma unroll
            for (int r = 0; r < 4; ++r) {
                long row = r0 + rg * 4 + r;
                if (row < N) {
                    float nm = norm[row];
                    float4 o;
                    o.x = acc[r][0] * nm; o.y = acc[r][1] * nm;
                    o.z = acc[r][2] * nm; o.w = acc[r][3] * nm;
                    *reinterpret_cast<float4*>(&z[row * DOUT + c0]) = o;
                }
            }
        }
    }
}

__global__ void final_kernel(float* __restrict__ out, const float* __restrict__ norm,
                             const float* __restrict__ b2, int N) {
    long total = (long)N * DOUT;
    long stride = (long)gridDim.x * blockDim.x;
    for (long i = (long)blockIdx.x * blockDim.x + threadIdx.x; i < total; i += stride) {
        int n = (int)(i / DOUT), d = (int)(i % DOUT);
        out[i] = fmaf(out[i], norm[n], b2[d]);
    }
}

// ---------------- launch ----------------

static inline size_t al4k(size_t x) { return (x + 4095) & ~(size_t)4095; }

extern "C" void kernel_launch(void* const* d_in, const int* in_sizes, int n_in,
                              void* d_out, int out_size, void* d_ws, size_t ws_size,
                              hipStream_t stream) {
    const float* feat = (const float*)d_in[0];
    const int*   src  = (const int*)d_in[1];
    const int*   dst  = (const int*)d_in[2];
    const float* W1   = (const float*)d_in[3];
    const float* b1   = (const float*)d_in[4];
    const float* W2   = (const float*)d_in[5];
    const float* b2   = (const float*)d_in[6];
    int N = in_sizes[0] / DIN;
    int E = in_sizes[1];
    float* out = (float*)d_out;
    char* ws = (char*)d_ws;

    int NB = (N + BNODES - 1) >> BSHIFT;
    int cap = ((E / (NB > 0 ? NB : 1)) * 5 / 4 + 256 + 1) & ~1;

    size_t o_norm   = 0;
    size_t o_rowptr = o_norm   + al4k((size_t)N * 4);
    size_t o_bcur   = o_rowptr + al4k(((size_t)N + 1) * 4);
    size_t o_bbase  = o_bcur   + al4k((size_t)(NB + 1) * 4);
    size_t o_esrc   = o_bbase  + al4k((size_t)(NB + 1) * 4);
    size_t o_aggh   = o_esrc   + al4k((size_t)E * 4);       // bucketbuf aliases aggh
    size_t o_y      = o_aggh   + al4k((size_t)N * DIN * 2);
    size_t o_z      = o_y      + al4k((size_t)N * DIN * 2);
    size_t need     = o_z      + al4k((size_t)N * DOUT * 2);

    bool bb_fits = (size_t)NB * cap * 8 <= (size_t)N * DIN * 2;

    if (ws_size >= need && NB <= 256 && bb_fits) {
        float*  norm   = (float*)(ws + o_norm);
        int*    rowptr = (int*)(ws + o_rowptr);
        int*    bcur   = (int*)(ws + o_bcur);
        int*    bbase  = (int*)(ws + o_bbase);
        int*    esrc   = (int*)(ws + o_esrc);
        __half* aggh   = (__half*)(ws + o_aggh);
        int2*   bbuf   = (int2*)(ws + o_aggh);
        __half* y      = (__half*)(ws + o_y);
        __half* z      = (__half*)(ws + o_z);

        hipMemsetAsync(bcur, 0, (size_t)(NB + 1) * 4, stream);

        int p1grid = (E + 8191) / 8192;
        pass1_bucket<<<p1grid, 256, 0, stream>>>(src, dst, E, NB, cap, bcur, bbuf);
        bucket_scan<<<1, 1, 0, stream>>>(bcur, bbase, NB);
        pass2_sort<<<NB, 256, 0, stream>>>(bbuf, bcur, bbase, N, NB, cap, norm, rowptr, esrc);
        yconv_kernel<<<4096, 256, 0, stream>>>(feat, norm, y, N);

        gather1_kernel<<<(N * 32 + 255) / 256, 256, 0, stream>>>(y, rowptr, esrc, aggh, N);
        mm1_kernel<<<(N + 31) / 32, 256, 0, stream>>>(aggh, W1, b1, norm, N);
        mm2_kernel<<<(N + 63) / 64, 256, 0, stream>>>(aggh, W2, norm, z, N);
        gather2_kernel<<<(N * 16 + 255) / 256, 256, 0, stream>>>(z, rowptr, esrc, norm, b2, out, N);
    } else {
        size_t f_norm = 0;
        size_t f_agg  = f_norm + al4k((size_t)N * 4);
        size_t f_z    = f_agg  + al4k((size_t)N * DIN * 4);
        float* norm = (float*)(ws + f_norm);
        float* agg  = (float*)(ws + f_agg);
        float* z    = (float*)(ws + f_z);
        int*   degi = (int*)(ws + f_norm);

        hipMemsetAsync(degi, 0, (size_t)N * 4, stream);
        hipMemsetAsync(agg, 0, (size_t)N * DIN * 4, stream);
        hipMemsetAsync(d_out, 0, (size_t)N * DOUT * 4, stream);

        degi_kernel<<<1024, 256, 0, stream>>>(dst, E, degi);
        norm_from_deg<<<(N + 255) / 256, 256, 0, stream>>>(degi, (float*)degi, N);
        scatter1_kernel<<<4096, 256, 0, stream>>>(feat, src, dst, norm, agg, E);
        mm1f_kernel<<<(N + 31) / 32, 256, 0, stream>>>(agg, W1, b1, norm, N);
        mm2f_kernel<<<(N + 63) / 64, 256, 0, stream>>>(agg, W2, norm, z, N);
        scatter2_kernel<<<4096, 256, 0, stream>>>(z, src, dst, out, E);
        final_kernel<<<4096, 256, 0, stream>>>(out, norm, b2, N);
    }
}

// Round 6
// 308.284 us; speedup vs baseline: 1.6536x; 1.0132x over previous
//
#include <hip/hip_runtime.h>
#include <hip/hip_fp16.h>
#include <math.h>

// SGC 2-layer: out = A_hat * elu(A_hat * X * W1 + b1) * W2 + b2
// A_hat = D^-1/2 A D^-1/2 (in-degree based, clip(deg,1))
// R2: CSR build + gather aggregation (no float atomics).
// R3: unroll-4 gathers -> REGRESSED (latency not the limiter); reverted.
// R4: CSR via two-level counting sort. 510->348us.
// R5: fp16 gather operands (y=feat*norm, agg/h, z). 348->312us, gather1 83us.
// R6: gather1 16B/lane (16 lanes/node) halves VMEM instr count; chunk-local
//     degree-sorted perm equalizes wave lanes' loop counts; bbuf packed to
//     one int ((s<<9)|dlocal) halves pass1/pass2 traffic; gather2 8 lanes
//     with uint4 loads.

#define DIN  128
#define DHID 128
#define DOUT 40
#define BSHIFT 9
#define BNODES 512   // 1 << BSHIFT

union U8  { uint2 u; __half2 h[2]; };
union U16 { uint4 u; __half2 h[4]; };

__device__ __forceinline__ float elu_f(float x) {
    return x > 0.0f ? x : (expf(x) - 1.0f);
}

// ---------------- CSR build (two-level counting sort, packed records) ----------------

__global__ void pass1_bucket(const int* __restrict__ src, const int* __restrict__ dst,
                             int E, int NB, int cap,
                             int* __restrict__ bcur, int* __restrict__ bbuf) {
    __shared__ int cnt[256];
    __shared__ int wcur[256];
    const int CHUNK = 8192;
    for (long base = (long)blockIdx.x * CHUNK; base < E; base += (long)gridDim.x * CHUNK) {
        int n = min(CHUNK, (int)(E - base));
        if (threadIdx.x < 256) cnt[threadIdx.x] = 0;
        __syncthreads();
        for (int i = threadIdx.x; i < n; i += blockDim.x) {
            int b = dst[base + i] >> BSHIFT;
            atomicAdd(&cnt[b], 1);
        }
        __syncthreads();
        if (threadIdx.x < NB) {
            int c = cnt[threadIdx.x];
            wcur[threadIdx.x] = (c > 0) ? atomicAdd(&bcur[threadIdx.x], c) : 0;
        }
        __syncthreads();
        for (int i = threadIdx.x; i < n; i += blockDim.x) {
            int s = src[base + i];
            int d = dst[base + i];
            int b = d >> BSHIFT;
            int slot = atomicAdd(&wcur[b], 1);
            if (slot < cap) bbuf[(long)b * cap + slot] = (s << BSHIFT) | (d & (BNODES - 1));
        }
        __syncthreads();
    }
}

__global__ void bucket_scan(const int* __restrict__ bcur, int* __restrict__ bbase, int NB) {
    if (blockIdx.x == 0 && threadIdx.x == 0) {
        int run = 0;
        for (int b = 0; b < NB; ++b) { bbase[b] = run; run += bcur[b]; }
        bbase[NB] = run;
    }
}

// per-bucket LDS counting sort -> norm, rowptr, esrc
__global__ void pass2_sort(const int* __restrict__ bbuf, const int* __restrict__ bcur,
                           const int* __restrict__ bbase, int N, int NB, int cap,
                           float* __restrict__ norm, int* __restrict__ rowptr,
                           int* __restrict__ esrc) {
    __shared__ int cnt[BNODES];
    int b = blockIdx.x;
    int n_b = min(bcur[b], cap);
    int gbase = bbase[b];
    int dbase = b << BSHIFT;
    const int* eb = bbuf + (long)b * cap;
    for (int i = threadIdx.x; i < BNODES; i += blockDim.x) cnt[i] = 0;
    __syncthreads();
    for (int i = threadIdx.x; i < n_b; i += blockDim.x)
        atomicAdd(&cnt[eb[i] & (BNODES - 1)], 1);
    __syncthreads();
    for (int i = threadIdx.x; i < BNODES; i += blockDim.x) {
        int d = dbase + i;
        if (d < N) norm[d] = rsqrtf(fmaxf((float)cnt[i], 1.0f));
    }
    __syncthreads();
    if (threadIdx.x == 0) {
        int run = 0;
        #pragma unroll 4
        for (int i = 0; i < BNODES; ++i) { int c = cnt[i]; cnt[i] = run; run += c; }
    }
    __syncthreads();
    for (int i = threadIdx.x; i < BNODES; i += blockDim.x) {
        int d = dbase + i;
        if (d < N) rowptr[d] = gbase + cnt[i];
    }
    if (b == NB - 1 && threadIdx.x == 0) rowptr[N] = bbase[NB];
    __syncthreads();
    for (int i = threadIdx.x; i < n_b; i += blockDim.x) {
        int v = eb[i];
        int slot = atomicAdd(&cnt[v & (BNODES - 1)], 1);
        esrc[gbase + slot] = ((unsigned)v) >> BSHIFT;
    }
}

// chunk-local degree sort: perm[base..base+n) = nodes of chunk ordered by degree.
// Only neighbor-equality matters (waves take consecutive perm entries).
__global__ void perm_build(const int* __restrict__ rowptr, int* __restrict__ perm, int N) {
    __shared__ int lcnt[1024];
    __shared__ int lbase[1024];
    const int CHUNK = 4096;
    for (long base = (long)blockIdx.x * CHUNK; base < N; base += (long)gridDim.x * CHUNK) {
        int n = min(CHUNK, (int)(N - base));
        for (int i = threadIdx.x; i < 1024; i += 256) lcnt[i] = 0;
        __syncthreads();
        for (int i = threadIdx.x; i < n; i += 256) {
            int d = min(rowptr[base + i + 1] - rowptr[base + i], 1023);
            atomicAdd(&lcnt[d], 1);
        }
        __syncthreads();
        if (threadIdx.x == 0) {
            int run = 0;
            for (int i = 0; i < 1024; ++i) { int c = lcnt[i]; lbase[i] = run; run += c; }
        }
        __syncthreads();
        for (int i = threadIdx.x; i < 1024; i += 256) lcnt[i] = 0;
        __syncthreads();
        for (int i = threadIdx.x; i < n; i += 256) {
            int d = min(rowptr[base + i + 1] - rowptr[base + i], 1023);
            int pos = lbase[d] + atomicAdd(&lcnt[d], 1);
            perm[base + pos] = base + (int)i;
        }
        __syncthreads();
    }
}

__global__ void norm_from_deg(const int* __restrict__ deg, float* __restrict__ norm, int N) {
    int stride = gridDim.x * blockDim.x;
    for (int i = blockIdx.x * blockDim.x + threadIdx.x; i < N; i += stride)
        norm[i] = rsqrtf(fmaxf((float)deg[i], 1.0f));
}

__global__ void degi_kernel(const int* __restrict__ dst, int E, int* __restrict__ deg) {
    int stride = gridDim.x * blockDim.x;
    for (int i = blockIdx.x * blockDim.x + threadIdx.x; i < E; i += stride)
        atomicAdd(&deg[dst[i]], 1);
}

// ---------------- fp16 staging + gathers ----------------

// y[n][d] = fp16(feat[n][d] * norm[n])
__global__ void yconv_kernel(const float* __restrict__ feat, const float* __restrict__ norm,
                             __half* __restrict__ y, int N) {
    long total = (long)N * 32;   // float4 groups
    long stride = (long)gridDim.x * blockDim.x;
    const float4* f4 = reinterpret_cast<const float4*>(feat);
    uint2* y2 = reinterpret_cast<uint2*>(y);
    for (long i = (long)blockIdx.x * blockDim.x + threadIdx.x; i < total; i += stride) {
        int n = (int)(i >> 5);
        float nm = norm[n];
        float4 v = f4[i];
        U8 o;
        o.h[0] = __floats2half2_rn(v.x * nm, v.y * nm);
        o.h[1] = __floats2half2_rn(v.z * nm, v.w * nm);
        y2[i] = o.u;
    }
}

// aggh[n] = fp16( sum_j y[esrc[j]] ) ; 16 lanes per node, uint4 (8 halves)/lane.
__global__ void gather1_kernel(const __half* __restrict__ y, const int* __restrict__ rowptr,
                               const int* __restrict__ esrc, const int* __restrict__ perm,
                               __half* __restrict__ aggh, int N) {
    int lane = threadIdx.x & 15;
    long g = ((long)blockIdx.x * blockDim.x + threadIdx.x) >> 4;
    long gstride = ((long)gridDim.x * blockDim.x) >> 4;
    const uint4* y4 = reinterpret_cast<const uint4*>(y);
    uint4* a4 = reinterpret_cast<uint4*>(aggh);
    for (long gi = g; gi < N; gi += gstride) {
        int n = perm[gi];
        int beg = rowptr[n], end = rowptr[n + 1];
        float a0 = 0.f, a1 = 0.f, a2 = 0.f, a3 = 0.f;
        float a4f = 0.f, a5 = 0.f, a6 = 0.f, a7 = 0.f;
        int j = beg;
        for (; j + 1 < end; j += 2) {
            int s0 = esrc[j], s1 = esrc[j + 1];
            U16 u0, u1;
            u0.u = y4[(long)s0 * 16 + lane];
            u1.u = y4[(long)s1 * 16 + lane];
            float2 p0 = __half22float2(u0.h[0]), p1 = __half22float2(u0.h[1]);
            float2 p2 = __half22float2(u0.h[2]), p3 = __half22float2(u0.h[3]);
            float2 q0 = __half22float2(u1.h[0]), q1 = __half22float2(u1.h[1]);
            float2 q2 = __half22float2(u1.h[2]), q3 = __half22float2(u1.h[3]);
            a0 += p0.x + q0.x; a1 += p0.y + q0.y;
            a2 += p1.x + q1.x; a3 += p1.y + q1.y;
            a4f += p2.x + q2.x; a5 += p2.y + q2.y;
            a6 += p3.x + q3.x; a7 += p3.y + q3.y;
        }
        if (j < end) {
            int s0 = esrc[j];
            U16 u0; u0.u = y4[(long)s0 * 16 + lane];
            float2 p0 = __half22float2(u0.h[0]), p1 = __half22float2(u0.h[1]);
            float2 p2 = __half22float2(u0.h[2]), p3 = __half22float2(u0.h[3]);
            a0 += p0.x; a1 += p0.y; a2 += p1.x; a3 += p1.y;
            a4f += p2.x; a5 += p2.y; a6 += p3.x; a7 += p3.y;
        }
        U16 o;
        o.h[0] = __floats2half2_rn(a0, a1);
        o.h[1] = __floats2half2_rn(a2, a3);
        o.h[2] = __floats2half2_rn(a4f, a5);
        o.h[3] = __floats2half2_rn(a6, a7);
        a4[(long)n * 16 + lane] = o.u;
    }
}

// out[n] = norm[n] * sum_j z[esrc[j]] + b2 ; 8 lanes per node, 5 active (uint4 each).
__global__ void gather2_kernel(const __half* __restrict__ z, const int* __restrict__ rowptr,
                               const int* __restrict__ esrc, const int* __restrict__ perm,
                               const float* __restrict__ norm, const float* __restrict__ b2,
                               float* __restrict__ out, int N) {
    int lane = threadIdx.x & 7;
    long g = ((long)blockIdx.x * blockDim.x + threadIdx.x) >> 3;
    long gstride = ((long)gridDim.x * blockDim.x) >> 3;
    const uint4* z4 = reinterpret_cast<const uint4*>(z);   // row = 5 uint4 (80B, 16B-aligned)
    for (long gi = g; gi < N; gi += gstride) {
        int n = perm[gi];
        if (lane < 5) {
            int beg = rowptr[n], end = rowptr[n + 1];
            float a0 = 0.f, a1 = 0.f, a2 = 0.f, a3 = 0.f;
            float a4f = 0.f, a5 = 0.f, a6 = 0.f, a7 = 0.f;
            int j = beg;
            for (; j + 1 < end; j += 2) {
                int s0 = esrc[j], s1 = esrc[j + 1];
                U16 u0, u1;
                u0.u = z4[(long)s0 * 5 + lane];
                u1.u = z4[(long)s1 * 5 + lane];
                float2 p0 = __half22float2(u0.h[0]), p1 = __half22float2(u0.h[1]);
                float2 p2 = __half22float2(u0.h[2]), p3 = __half22float2(u0.h[3]);
                float2 q0 = __half22float2(u1.h[0]), q1 = __half22float2(u1.h[1]);
                float2 q2 = __half22float2(u1.h[2]), q3 = __half22float2(u1.h[3]);
                a0 += p0.x + q0.x; a1 += p0.y + q0.y;
                a2 += p1.x + q1.x; a3 += p1.y + q1.y;
                a4f += p2.x + q2.x; a5 += p2.y + q2.y;
                a6 += p3.x + q3.x; a7 += p3.y + q3.y;
            }
            if (j < end) {
                int s0 = esrc[j];
                U16 u0; u0.u = z4[(long)s0 * 5 + lane];
                float2 p0 = __half22float2(u0.h[0]), p1 = __half22float2(u0.h[1]);
                float2 p2 = __half22float2(u0.h[2]), p3 = __half22float2(u0.h[3]);
                a0 += p0.x; a1 += p0.y; a2 += p1.x; a3 += p1.y;
                a4f += p2.x; a5 += p2.y; a6 += p3.x; a7 += p3.y;
            }
            float nm = norm[n];
            const float4* b4 = reinterpret_cast<const float4*>(b2);
            float4 bb0 = b4[lane * 2], bb1 = b4[lane * 2 + 1];
            float4 o0, o1;
            o0.x = fmaf(a0, nm, bb0.x); o0.y = fmaf(a1, nm, bb0.y);
            o0.z = fmaf(a2, nm, bb0.z); o0.w = fmaf(a3, nm, bb0.w);
            o1.x = fmaf(a4f, nm, bb1.x); o1.y = fmaf(a5, nm, bb1.y);
            o1.z = fmaf(a6, nm, bb1.z); o1.w = fmaf(a7, nm, bb1.w);
            float4* out4 = reinterpret_cast<float4*>(out);
            out4[(long)n * 10 + lane * 2] = o0;
            out4[(long)n * 10 + lane * 2 + 1] = o1;
        }
    }
}

// ---------------- dense matmuls (fp16 in/out, fp32 math) ----------------

// h[n] = fp16( elu( (aggh[n]*norm[n]) @ W1 + b1 ) ), in-place on aggh.
__launch_bounds__(256, 2)
__global__ void mm1_kernel(__half* __restrict__ xh, const float* __restrict__ W1,
                           const float* __restrict__ b1, const float* __restrict__ norm,
                           int N) {
    __shared__ float Wl[DIN * DHID];   // 64KB
    __shared__ float Xl[32 * DIN];     // 16KB
    for (int i = threadIdx.x; i < DIN * DHID; i += 256) Wl[i] = W1[i];
    int cg = threadIdx.x & 31;
    int rg = threadIdx.x >> 5;
    int c0 = cg * 4;
    for (long r0 = (long)blockIdx.x * 32; r0 < N; r0 += (long)gridDim.x * 32) {
        __syncthreads();
        for (int i = threadIdx.x; i < 32 * 32; i += 256) {
            int rr = i >> 5;
            long row = r0 + rr;
            float4 v = make_float4(0.f, 0.f, 0.f, 0.f);
            if (row < N) {
                U8 u; u.u = reinterpret_cast<const uint2*>(xh)[row * 32 + (i & 31)];
                float2 f0 = __half22float2(u.h[0]), f1 = __half22float2(u.h[1]);
                float nm = norm[row];
                v = make_float4(f0.x * nm, f0.y * nm, f1.x * nm, f1.y * nm);
            }
            reinterpret_cast<float4*>(Xl)[i] = v;
        }
        __syncthreads();
        float acc[4][4];
        float bx = b1[c0], by = b1[c0 + 1], bz = b1[c0 + 2], bw = b1[c0 + 3];
        #pragma unroll
        for (int r = 0; r < 4; ++r) { acc[r][0] = bx; acc[r][1] = by; acc[r][2] = bz; acc[r][3] = bw; }
        for (int k = 0; k < DIN; k += 4) {
            float4 w0 = *reinterpret_cast<const float4*>(&Wl[(k + 0) * DHID + c0]);
            float4 w1 = *reinterpret_cast<const float4*>(&Wl[(k + 1) * DHID + c0]);
            float4 w2 = *reinterpret_cast<const float4*>(&Wl[(k + 2) * DHID + c0]);
            float4 w3 = *reinterpret_cast<const float4*>(&Wl[(k + 3) * DHID + c0]);
            #pragma unroll
            for (int r = 0; r < 4; ++r) {
                float4 x = *reinterpret_cast<const float4*>(&Xl[(rg * 4 + r) * DIN + k]);
                acc[r][0] = fmaf(x.x, w0.x, fmaf(x.y, w1.x, fmaf(x.z, w2.x, fmaf(x.w, w3.x, acc[r][0]))));
                acc[r][1] = fmaf(x.x, w0.y, fmaf(x.y, w1.y, fmaf(x.z, w2.y, fmaf(x.w, w3.y, acc[r][1]))));
                acc[r][2] = fmaf(x.x, w0.z, fmaf(x.y, w1.z, fmaf(x.z, w2.z, fmaf(x.w, w3.z, acc[r][2]))));
                acc[r][3] = fmaf(x.x, w0.w, fmaf(x.y, w1.w, fmaf(x.z, w2.w, fmaf(x.w, w3.w, acc[r][3]))));
            }
        }
        #pragma unroll
        for (int r = 0; r < 4; ++r) {
            long row = r0 + rg * 4 + r;
            if (row < N) {
                U8 o;
                o.h[0] = __floats2half2_rn(elu_f(acc[r][0]), elu_f(acc[r][1]));
                o.h[1] = __floats2half2_rn(elu_f(acc[r][2]), elu_f(acc[r][3]));
                reinterpret_cast<uint2*>(xh)[row * 32 + cg] = o.u;
            }
        }
    }
}

// z[n] = fp16( norm[n] * (h[n] @ W2) )
__launch_bounds__(256, 2)
__global__ void mm2_kernel(const __half* __restrict__ h, const float* __restrict__ W2,
                           const float* __restrict__ norm, __half* __restrict__ z, int N) {
    __shared__ float Wl[DHID * DOUT];
    __shared__ float Xl[64 * DIN];
    for (int i = threadIdx.x; i < DHID * DOUT; i += 256) Wl[i] = W2[i];
    int cg = threadIdx.x & 15;
    int rg = threadIdx.x >> 4;
    int c0 = cg * 4;
    for (long r0 = (long)blockIdx.x * 64; r0 < N; r0 += (long)gridDim.x * 64) {
        __syncthreads();
        for (int i = threadIdx.x; i < 64 * 32; i += 256) {
            int rr = i >> 5;
            long row = r0 + rr;
            float4 v = make_float4(0.f, 0.f, 0.f, 0.f);
            if (row < N) {
                U8 u; u.u = reinterpret_cast<const uint2*>(h)[row * 32 + (i & 31)];
                float2 f0 = __half22float2(u.h[0]), f1 = __half22float2(u.h[1]);
                v = make_float4(f0.x, f0.y, f1.x, f1.y);
            }
            reinterpret_cast<float4*>(Xl)[i] = v;
        }
        __syncthreads();
        if (c0 < DOUT) {
            float acc[4][4];
            #pragma unroll
            for (int r = 0; r < 4; ++r) { acc[r][0] = 0.f; acc[r][1] = 0.f; acc[r][2] = 0.f; acc[r][3] = 0.f; }
            for (int k = 0; k < DHID; k += 4) {
                float4 w0 = *reinterpret_cast<const float4*>(&Wl[(k + 0) * DOUT + c0]);
                float4 w1 = *reinterpret_cast<const float4*>(&Wl[(k + 1) * DOUT + c0]);
                float4 w2 = *reinterpret_cast<const float4*>(&Wl[(k + 2) * DOUT + c0]);
                float4 w3 = *reinterpret_cast<const float4*>(&Wl[(k + 3) * DOUT + c0]);
                #pragma unroll
                for (int r = 0; r < 4; ++r) {
                    float4 x = *reinterpret_cast<const float4*>(&Xl[(rg * 4 + r) * DIN + k]);
                    acc[r][0] = fmaf(x.x, w0.x, fmaf(x.y, w1.x, fmaf(x.z, w2.x, fmaf(x.w, w3.x, acc[r][0]))));
                    acc[r][1] = fmaf(x.x, w0.y, fmaf(x.y, w1.y, fmaf(x.z, w2.y, fmaf(x.w, w3.y, acc[r][1]))));
                    acc[r][2] = fmaf(x.x, w0.z, fmaf(x.y, w1.z, fmaf(x.z, w2.z, fmaf(x.w, w3.z, acc[r][2]))));
                    acc[r][3] = fmaf(x.x, w0.w, fmaf(x.y, w1.w, fmaf(x.z, w2.w, fmaf(x.w, w3.w, acc[r][3]))));
                }
            }
            #pragma unroll
            for (int r = 0; r < 4; ++r) {
                long row = r0 + rg * 4 + r;
                if (row < N) {
                    float nm = norm[row];
                    U8 o;
                    o.h[0] = __floats2half2_rn(acc[r][0] * nm, acc[r][1] * nm);
                    o.h[1] = __floats2half2_rn(acc[r][2] * nm, acc[r][3] * nm);
                    reinterpret_cast<uint2*>(z)[row * 10 + cg] = o.u;
                }
            }
        }
    }
}

// ---------------- fallback (f32 atomic path) ----------------

__global__ void scatter1_kernel(const float* __restrict__ feat, const int* __restrict__ src,
                                const int* __restrict__ dst, const float* __restrict__ norm,
                                float* __restrict__ agg, int E) {
    long T = (long)blockIdx.x * blockDim.x + threadIdx.x;
    int l4 = (int)(T & 31);
    long e = T >> 5;
    long estride = ((long)gridDim.x * blockDim.x) >> 5;
    for (; e < E; e += estride) {
        int s = src[e], d = dst[e];
        float ns = norm[s];
        float4 v = reinterpret_cast<const float4*>(feat)[(long)s * 32 + l4];
        float* o = agg + (long)d * DIN + l4 * 4;
        atomicAdd(o + 0, v.x * ns);
        atomicAdd(o + 1, v.y * ns);
        atomicAdd(o + 2, v.z * ns);
        atomicAdd(o + 3, v.w * ns);
    }
}

__global__ void scatter2_kernel(const float* __restrict__ z, const int* __restrict__ src,
                                const int* __restrict__ dst, float* __restrict__ out, int E) {
    long T = (long)blockIdx.x * blockDim.x + threadIdx.x;
    int l = (int)(T & 15);
    long e = T >> 4;
    long estride = ((long)gridDim.x * blockDim.x) >> 4;
    for (; e < E; e += estride) {
        if (l < 10) {
            int s = src[e], d = dst[e];
            float4 v = reinterpret_cast<const float4*>(z)[(long)s * 10 + l];
            float* o = out + (long)d * DOUT + l * 4;
            atomicAdd(o + 0, v.x);
            atomicAdd(o + 1, v.y);
            atomicAdd(o + 2, v.z);
            atomicAdd(o + 3, v.w);
        }
    }
}

__launch_bounds__(256, 2)
__global__ void mm1f_kernel(float* __restrict__ xh, const float* __restrict__ W1,
                            const float* __restrict__ b1, const float* __restrict__ norm,
                            int N) {
    __shared__ float Wl[DIN * DHID];
    __shared__ float Xl[32 * DIN];
    for (int i = threadIdx.x; i < DIN * DHID; i += 256) Wl[i] = W1[i];
    int cg = threadIdx.x & 31;
    int rg = threadIdx.x >> 5;
    int c0 = cg * 4;
    for (long r0 = (long)blockIdx.x * 32; r0 < N; r0 += (long)gridDim.x * 32) {
        __syncthreads();
        for (int i = threadIdx.x; i < 32 * 32; i += 256) {
            int rr = i >> 5;
            long row = r0 + rr;
            float4 v = make_float4(0.f, 0.f, 0.f, 0.f);
            if (row < N) {
                v = reinterpret_cast<const float4*>(xh)[row * 32 + (i & 31)];
                float nm = norm[row];
                v.x *= nm; v.y *= nm; v.z *= nm; v.w *= nm;
            }
            reinterpret_cast<float4*>(Xl)[i] = v;
        }
        __syncthreads();
        float acc[4][4];
        float bx = b1[c0], by = b1[c0 + 1], bz = b1[c0 + 2], bw = b1[c0 + 3];
        #pragma unroll
        for (int r = 0; r < 4; ++r) { acc[r][0] = bx; acc[r][1] = by; acc[r][2] = bz; acc[r][3] = bw; }
        for (int k = 0; k < DIN; k += 4) {
            float4 w0 = *reinterpret_cast<const float4*>(&Wl[(k + 0) * DHID + c0]);
            float4 w1 = *reinterpret_cast<const float4*>(&Wl[(k + 1) * DHID + c0]);
            float4 w2 = *reinterpret_cast<const float4*>(&Wl[(k + 2) * DHID + c0]);
            float4 w3 = *reinterpret_cast<const float4*>(&Wl[(k + 3) * DHID + c0]);
            #pragma unroll
            for (int r = 0; r < 4; ++r) {
                float4 x = *reinterpret_cast<const float4*>(&Xl[(rg * 4 + r) * DIN + k]);
                acc[r][0] = fmaf(x.x, w0.x, fmaf(x.y, w1.x, fmaf(x.z, w2.x, fmaf(x.w, w3.x, acc[r][0]))));
                acc[r][1] = fmaf(x.x, w0.y, fmaf(x.y, w1.y, fmaf(x.z, w2.y, fmaf(x.w, w3.y, acc[r][1]))));
                acc[r][2] = fmaf(x.x, w0.z, fmaf(x.y, w1.z, fmaf(x.z, w2.z, fmaf(x.w, w3.z, acc[r][2]))));
                acc[r][3] = fmaf(x.x, w0.w, fmaf(x.y, w1.w, fmaf(x.z, w2.w, fmaf(x.w, w3.w, acc[r][3]))));
            }
        }
        #pragma unroll
        for (int r = 0; r < 4; ++r) {
            long row = r0 + rg * 4 + r;
            if (row < N) {
                float4 o;
                o.x = elu_f(acc[r][0]); o.y = elu_f(acc[r][1]);
                o.z = elu_f(acc[r][2]); o.w = elu_f(acc[r][3]);
                *reinterpret_cast<float4*>(&xh[row * DIN + c0]) = o;
            }
        }
    }
}

__launch_bounds__(256, 2)
__global__ void mm2f_kernel(const float* __restrict__ h, const float* __restrict__ W2,
                            const float* __restrict__ norm, float* __restrict__ z, int N) {
    __shared__ float Wl[DHID * DOUT];
    __shared__ float Xl[64 * DIN];
    for (int i = threadIdx.x; i < DHID * DOUT; i += 256) Wl[i] = W2[i];
    int cg = threadIdx.x & 15;
    int rg = threadIdx.x >> 4;
    int c0 = cg * 4;
    for (long r0 = (long)blockIdx.x * 64; r0 < N; r0 += (long)gridDim.x * 64) {
        __syncthreads();
        for (int i = threadIdx.x; i < 64 * 32; i += 256) {
            int rr = i >> 5;
            long row = r0 + rr;
            float4 v = make_float4(0.f, 0.f, 0.f, 0.f);
            if (row < N) v = reinterpret_cast<const float4*>(h)[row * 32 + (i & 31)];
            reinterpret_cast<float4*>(Xl)[i] = v;
        }
        __syncthreads();
        if (c0 < DOUT) {
            float acc[4][4];
            #pragma unroll
            for (int r = 0; r < 4; ++r) { acc[r][0] = 0.f; acc[r][1] = 0.f; acc[r][2] = 0.f; acc[r][3] = 0.f; }
            for (int k = 0; k < DHID; k += 4) {
                float4 w0 = *reinterpret_cast<const float4*>(&Wl[(k + 0) * DOUT + c0]);
                float4 w1 = *reinterpret_cast<const float4*>(&Wl[(k + 1) * DOUT + c0]);
                float4 w2 = *reinterpret_cast<const float4*>(&Wl[(k + 2) * DOUT + c0]);
                float4 w3 = *reinterpret_cast<const float4*>(&Wl[(k + 3) * DOUT + c0]);
                #pragma unroll
                for (int r = 0; r < 4; ++r) {
                    float4 x = *reinterpret_cast<const float4*>(&Xl[(rg * 4 + r) * DIN + k]);
                    acc[r][0] = fmaf(x.x, w0.x, fmaf(x.y, w1.x, fmaf(x.z, w2.x, fmaf(x.w, w3.x, acc[r][0]))));
                    acc[r][1] = fmaf(x.x, w0.y, fmaf(x.y, w1.y, fmaf(x.z, w2.y, fmaf(x.w, w3.y, acc[r][1]))));
                    acc[r][2] = fmaf(x.x, w0.z, fmaf(x.y, w1.z, fmaf(x.z, w2.z, fmaf(x.w, w3.z, acc[r][2]))));
                    acc[r][3] = fmaf(x.x, w0.w, fmaf(x.y, w1.w, fmaf(x.z, w2.w, fmaf(x.w, w3.w, acc[r][3]))));
                }
            }
            #pragma unroll
            for (int r = 0; r < 4; ++r) {
                long row = r0 + rg * 4 + r;
                if (row < N) {
                    float nm = norm[row];
                    float4 o;
                    o.x = acc[r][0] * nm; o.y = acc[r][1] * nm;
                    o.z = acc[r][2] * nm; o.w = acc[r][3] * nm;
                    *reinterpret_cast<float4*>(&z[row * DOUT + c0]) = o;
                }
            }
        }
    }
}

__global__ void final_kernel(float* __restrict__ out, const float* __restrict__ norm,
                             const float* __restrict__ b2, int N) {
    long total = (long)N * DOUT;
    long stride = (long)gridDim.x * blockDim.x;
    for (long i = (long)blockIdx.x * blockDim.x + threadIdx.x; i < total; i += stride) {
        int n = (int)(i / DOUT), d = (int)(i % DOUT);
        out[i] = fmaf(out[i], norm[n], b2[d]);
    }
}

// ---------------- launch ----------------

static inline size_t al4k(size_t x) { return (x + 4095) & ~(size_t)4095; }

extern "C" void kernel_launch(void* const* d_in, const int* in_sizes, int n_in,
                              void* d_out, int out_size, void* d_ws, size_t ws_size,
                              hipStream_t stream) {
    const float* feat = (const float*)d_in[0];
    const int*   src  = (const int*)d_in[1];
    const int*   dst  = (const int*)d_in[2];
    const float* W1   = (const float*)d_in[3];
    const float* b1   = (const float*)d_in[4];
    const float* W2   = (const float*)d_in[5];
    const float* b2   = (const float*)d_in[6];
    int N = in_sizes[0] / DIN;
    int E = in_sizes[1];
    float* out = (float*)d_out;
    char* ws = (char*)d_ws;

    int NB = (N + BNODES - 1) >> BSHIFT;
    int cap = ((E / (NB > 0 ? NB : 1)) * 5 / 4 + 256 + 1) & ~1;

    size_t o_norm   = 0;
    size_t o_rowptr = o_norm   + al4k((size_t)N * 4);
    size_t o_bcur   = o_rowptr + al4k(((size_t)N + 1) * 4);
    size_t o_bbase  = o_bcur   + al4k((size_t)(NB + 1) * 4);
    size_t o_perm   = o_bbase  + al4k((size_t)(NB + 1) * 4);
    size_t o_esrc   = o_perm   + al4k((size_t)N * 4);
    size_t o_aggh   = o_esrc   + al4k((size_t)E * 4);       // packed bucketbuf aliases aggh
    size_t o_y      = o_aggh   + al4k((size_t)N * DIN * 2);
    size_t o_z      = o_y      + al4k((size_t)N * DIN * 2);
    size_t need     = o_z      + al4k((size_t)N * DOUT * 2);

    bool bb_fits = (size_t)NB * cap * 4 <= (size_t)N * DIN * 2;
    bool packs   = N <= (1 << 22);

    if (ws_size >= need && NB <= 256 && bb_fits && packs) {
        float*  norm   = (float*)(ws + o_norm);
        int*    rowptr = (int*)(ws + o_rowptr);
        int*    bcur   = (int*)(ws + o_bcur);
        int*    bbase  = (int*)(ws + o_bbase);
        int*    perm   = (int*)(ws + o_perm);
        int*    esrc   = (int*)(ws + o_esrc);
        __half* aggh   = (__half*)(ws + o_aggh);
        int*    bbuf   = (int*)(ws + o_aggh);
        __half* y      = (__half*)(ws + o_y);
        __half* z      = (__half*)(ws + o_z);

        hipMemsetAsync(bcur, 0, (size_t)(NB + 1) * 4, stream);

        int p1grid = (E + 8191) / 8192;
        pass1_bucket<<<p1grid, 256, 0, stream>>>(src, dst, E, NB, cap, bcur, bbuf);
        bucket_scan<<<1, 1, 0, stream>>>(bcur, bbase, NB);
        pass2_sort<<<NB, 256, 0, stream>>>(bbuf, bcur, bbase, N, NB, cap, norm, rowptr, esrc);
        perm_build<<<(N + 4095) / 4096, 256, 0, stream>>>(rowptr, perm, N);
        yconv_kernel<<<4096, 256, 0, stream>>>(feat, norm, y, N);

        gather1_kernel<<<(N * 16 + 255) / 256, 256, 0, stream>>>(y, rowptr, esrc, perm, aggh, N);
        mm1_kernel<<<(N + 31) / 32, 256, 0, stream>>>(aggh, W1, b1, norm, N);
        mm2_kernel<<<(N + 63) / 64, 256, 0, stream>>>(aggh, W2, norm, z, N);
        gather2_kernel<<<(N * 8 + 255) / 256, 256, 0, stream>>>(z, rowptr, esrc, perm, norm, b2, out, N);
    } else {
        size_t f_norm = 0;
        size_t f_agg  = f_norm + al4k((size_t)N * 4);
        size_t f_z    = f_agg  + al4k((size_t)N * DIN * 4);
        float* norm = (float*)(ws + f_norm);
        float* agg  = (float*)(ws + f_agg);
        float* z    = (float*)(ws + f_z);
        int*   degi = (int*)(ws + f_norm);

        hipMemsetAsync(degi, 0, (size_t)N * 4, stream);
        hipMemsetAsync(agg, 0, (size_t)N * DIN * 4, stream);
        hipMemsetAsync(d_out, 0, (size_t)N * DOUT * 4, stream);

        degi_kernel<<<1024, 256, 0, stream>>>(dst, E, degi);
        norm_from_deg<<<(N + 255) / 256, 256, 0, stream>>>(degi, (float*)degi, N);
        scatter1_kernel<<<4096, 256, 0, stream>>>(feat, src, dst, norm, agg, E);
        mm1f_kernel<<<(N + 31) / 32, 256, 0, stream>>>(agg, W1, b1, norm, N);
        mm2f_kernel<<<(N + 63) / 64, 256, 0, stream>>>(agg, W2, norm, z, N);
        scatter2_kernel<<<4096, 256, 0, stream>>>(z, src, dst, out, E);
        final_kernel<<<4096, 256, 0, stream>>>(out, norm, b2, N);
    }
}

// Round 7
// 238.748 us; speedup vs baseline: 2.1353x; 1.2913x over previous
//
#include <hip/hip_runtime.h>
#include <hip/hip_fp16.h>
#include <math.h>

// SGC 2-layer: out = A_hat * elu(A_hat * X * W1 + b1) * W2 + b2
// A_hat = D^-1/2 A D^-1/2 (in-degree based, clip(deg,1))
// R2: CSR build + gather aggregation (no float atomics).
// R3: unroll-4 gathers -> REGRESSED; reverted.
// R4: CSR via two-level counting sort. 510->348us.
// R5: fp16 gather operands. 348->312us.
// R6: wide gather loads + degree-perm + packed CSR. 312->308us; mm1 now top (75us VALU-bound).
// R7: MFMA fp16 fused matmul: W1/W2 pre-packed to B-fragments, one kernel does
//     h=elu(X@W1+b1) (LDS-swizzled staging) then z=norm*(h@W2), h never hits global.
//     dst-norm folded into gather1 epilogue.

#define DIN  128
#define DHID 128
#define DOUT 40
#define BSHIFT 9
#define BNODES 512   // 1 << BSHIFT

union U8  { uint2 u; __half2 h[2]; };
union U16 { uint4 u; __half2 h[4]; };

typedef _Float16 f16x8 __attribute__((ext_vector_type(8)));
typedef float    f32x4 __attribute__((ext_vector_type(4)));
union F16X8 { uint4 u; f16x8 f; };
union HCV   { __half h; unsigned short s; };

__device__ __forceinline__ float elu_f(float x) {
    return x > 0.0f ? x : (expf(x) - 1.0f);
}

// ---------------- CSR build (two-level counting sort, packed records) ----------------

__global__ void pass1_bucket(const int* __restrict__ src, const int* __restrict__ dst,
                             int E, int NB, int cap,
                             int* __restrict__ bcur, int* __restrict__ bbuf) {
    __shared__ int cnt[256];
    __shared__ int wcur[256];
    const int CHUNK = 8192;
    for (long base = (long)blockIdx.x * CHUNK; base < E; base += (long)gridDim.x * CHUNK) {
        int n = min(CHUNK, (int)(E - base));
        if (threadIdx.x < 256) cnt[threadIdx.x] = 0;
        __syncthreads();
        for (int i = threadIdx.x; i < n; i += blockDim.x) {
            int b = dst[base + i] >> BSHIFT;
            atomicAdd(&cnt[b], 1);
        }
        __syncthreads();
        if (threadIdx.x < NB) {
            int c = cnt[threadIdx.x];
            wcur[threadIdx.x] = (c > 0) ? atomicAdd(&bcur[threadIdx.x], c) : 0;
        }
        __syncthreads();
        for (int i = threadIdx.x; i < n; i += blockDim.x) {
            int s = src[base + i];
            int d = dst[base + i];
            int b = d >> BSHIFT;
            int slot = atomicAdd(&wcur[b], 1);
            if (slot < cap) bbuf[(long)b * cap + slot] = (s << BSHIFT) | (d & (BNODES - 1));
        }
        __syncthreads();
    }
}

__global__ void bucket_scan(const int* __restrict__ bcur, int* __restrict__ bbase, int NB) {
    if (blockIdx.x == 0 && threadIdx.x == 0) {
        int run = 0;
        for (int b = 0; b < NB; ++b) { bbase[b] = run; run += bcur[b]; }
        bbase[NB] = run;
    }
}

// per-bucket LDS counting sort -> norm, rowptr, esrc
__global__ void pass2_sort(const int* __restrict__ bbuf, const int* __restrict__ bcur,
                           const int* __restrict__ bbase, int N, int NB, int cap,
                           float* __restrict__ norm, int* __restrict__ rowptr,
                           int* __restrict__ esrc) {
    __shared__ int cnt[BNODES];
    int b = blockIdx.x;
    int n_b = min(bcur[b], cap);
    int gbase = bbase[b];
    int dbase = b << BSHIFT;
    const int* eb = bbuf + (long)b * cap;
    for (int i = threadIdx.x; i < BNODES; i += blockDim.x) cnt[i] = 0;
    __syncthreads();
    for (int i = threadIdx.x; i < n_b; i += blockDim.x)
        atomicAdd(&cnt[eb[i] & (BNODES - 1)], 1);
    __syncthreads();
    for (int i = threadIdx.x; i < BNODES; i += blockDim.x) {
        int d = dbase + i;
        if (d < N) norm[d] = rsqrtf(fmaxf((float)cnt[i], 1.0f));
    }
    __syncthreads();
    if (threadIdx.x == 0) {
        int run = 0;
        #pragma unroll 4
        for (int i = 0; i < BNODES; ++i) { int c = cnt[i]; cnt[i] = run; run += c; }
    }
    __syncthreads();
    for (int i = threadIdx.x; i < BNODES; i += blockDim.x) {
        int d = dbase + i;
        if (d < N) rowptr[d] = gbase + cnt[i];
    }
    if (b == NB - 1 && threadIdx.x == 0) rowptr[N] = bbase[NB];
    __syncthreads();
    for (int i = threadIdx.x; i < n_b; i += blockDim.x) {
        int v = eb[i];
        int slot = atomicAdd(&cnt[v & (BNODES - 1)], 1);
        esrc[gbase + slot] = ((unsigned)v) >> BSHIFT;
    }
}

// chunk-local degree sort: perm[base..base+n) = nodes of chunk ordered by degree.
__global__ void perm_build(const int* __restrict__ rowptr, int* __restrict__ perm, int N) {
    __shared__ int lcnt[1024];
    __shared__ int lbase[1024];
    const int CHUNK = 4096;
    for (long base = (long)blockIdx.x * CHUNK; base < N; base += (long)gridDim.x * CHUNK) {
        int n = min(CHUNK, (int)(N - base));
        for (int i = threadIdx.x; i < 1024; i += 256) lcnt[i] = 0;
        __syncthreads();
        for (int i = threadIdx.x; i < n; i += 256) {
            int d = min(rowptr[base + i + 1] - rowptr[base + i], 1023);
            atomicAdd(&lcnt[d], 1);
        }
        __syncthreads();
        if (threadIdx.x == 0) {
            int run = 0;
            for (int i = 0; i < 1024; ++i) { int c = lcnt[i]; lbase[i] = run; run += c; }
        }
        __syncthreads();
        for (int i = threadIdx.x; i < 1024; i += 256) lcnt[i] = 0;
        __syncthreads();
        for (int i = threadIdx.x; i < n; i += 256) {
            int d = min(rowptr[base + i + 1] - rowptr[base + i], 1023);
            int pos = lbase[d] + atomicAdd(&lcnt[d], 1);
            perm[base + pos] = base + (int)i;
        }
        __syncthreads();
    }
}

__global__ void norm_from_deg(const int* __restrict__ deg, float* __restrict__ norm, int N) {
    int stride = gridDim.x * blockDim.x;
    for (int i = blockIdx.x * blockDim.x + threadIdx.x; i < N; i += stride)
        norm[i] = rsqrtf(fmaxf((float)deg[i], 1.0f));
}

__global__ void degi_kernel(const int* __restrict__ dst, int E, int* __restrict__ deg) {
    int stride = gridDim.x * blockDim.x;
    for (int i = blockIdx.x * blockDim.x + threadIdx.x; i < E; i += stride)
        atomicAdd(&deg[dst[i]], 1);
}

// ---------------- fp16 staging + gathers ----------------

// y[n][d] = fp16(feat[n][d] * norm[n])
__global__ void yconv_kernel(const float* __restrict__ feat, const float* __restrict__ norm,
                             __half* __restrict__ y, int N) {
    long total = (long)N * 32;
    long stride = (long)gridDim.x * blockDim.x;
    const float4* f4 = reinterpret_cast<const float4*>(feat);
    uint2* y2 = reinterpret_cast<uint2*>(y);
    for (long i = (long)blockIdx.x * blockDim.x + threadIdx.x; i < total; i += stride) {
        int n = (int)(i >> 5);
        float nm = norm[n];
        float4 v = f4[i];
        U8 o;
        o.h[0] = __floats2half2_rn(v.x * nm, v.y * nm);
        o.h[1] = __floats2half2_rn(v.z * nm, v.w * nm);
        y2[i] = o.u;
    }
}

// aggh[n] = fp16( norm[n] * sum_j y[esrc[j]] ) ; 16 lanes per node (dst-norm folded in).
__global__ void gather1_kernel(const __half* __restrict__ y, const int* __restrict__ rowptr,
                               const int* __restrict__ esrc, const int* __restrict__ perm,
                               const float* __restrict__ norm,
                               __half* __restrict__ aggh, int N) {
    int lane = threadIdx.x & 15;
    long g = ((long)blockIdx.x * blockDim.x + threadIdx.x) >> 4;
    long gstride = ((long)gridDim.x * blockDim.x) >> 4;
    const uint4* y4 = reinterpret_cast<const uint4*>(y);
    uint4* a4 = reinterpret_cast<uint4*>(aggh);
    for (long gi = g; gi < N; gi += gstride) {
        int n = perm[gi];
        int beg = rowptr[n], end = rowptr[n + 1];
        float a0 = 0.f, a1 = 0.f, a2 = 0.f, a3 = 0.f;
        float a4f = 0.f, a5 = 0.f, a6 = 0.f, a7 = 0.f;
        int j = beg;
        for (; j + 1 < end; j += 2) {
            int s0 = esrc[j], s1 = esrc[j + 1];
            U16 u0, u1;
            u0.u = y4[(long)s0 * 16 + lane];
            u1.u = y4[(long)s1 * 16 + lane];
            float2 p0 = __half22float2(u0.h[0]), p1 = __half22float2(u0.h[1]);
            float2 p2 = __half22float2(u0.h[2]), p3 = __half22float2(u0.h[3]);
            float2 q0 = __half22float2(u1.h[0]), q1 = __half22float2(u1.h[1]);
            float2 q2 = __half22float2(u1.h[2]), q3 = __half22float2(u1.h[3]);
            a0 += p0.x + q0.x; a1 += p0.y + q0.y;
            a2 += p1.x + q1.x; a3 += p1.y + q1.y;
            a4f += p2.x + q2.x; a5 += p2.y + q2.y;
            a6 += p3.x + q3.x; a7 += p3.y + q3.y;
        }
        if (j < end) {
            int s0 = esrc[j];
            U16 u0; u0.u = y4[(long)s0 * 16 + lane];
            float2 p0 = __half22float2(u0.h[0]), p1 = __half22float2(u0.h[1]);
            float2 p2 = __half22float2(u0.h[2]), p3 = __half22float2(u0.h[3]);
            a0 += p0.x; a1 += p0.y; a2 += p1.x; a3 += p1.y;
            a4f += p2.x; a5 += p2.y; a6 += p3.x; a7 += p3.y;
        }
        float nm = norm[n];
        U16 o;
        o.h[0] = __floats2half2_rn(a0 * nm, a1 * nm);
        o.h[1] = __floats2half2_rn(a2 * nm, a3 * nm);
        o.h[2] = __floats2half2_rn(a4f * nm, a5 * nm);
        o.h[3] = __floats2half2_rn(a6 * nm, a7 * nm);
        a4[(long)n * 16 + lane] = o.u;
    }
}

// out[n] = norm[n] * sum_j z[esrc[j]] + b2 ; 8 lanes per node, 5 active (uint4 each).
__global__ void gather2_kernel(const __half* __restrict__ z, const int* __restrict__ rowptr,
                               const int* __restrict__ esrc, const int* __restrict__ perm,
                               const float* __restrict__ norm, const float* __restrict__ b2,
                               float* __restrict__ out, int N) {
    int lane = threadIdx.x & 7;
    long g = ((long)blockIdx.x * blockDim.x + threadIdx.x) >> 3;
    long gstride = ((long)gridDim.x * blockDim.x) >> 3;
    const uint4* z4 = reinterpret_cast<const uint4*>(z);
    for (long gi = g; gi < N; gi += gstride) {
        int n = perm[gi];
        if (lane < 5) {
            int beg = rowptr[n], end = rowptr[n + 1];
            float a0 = 0.f, a1 = 0.f, a2 = 0.f, a3 = 0.f;
            float a4f = 0.f, a5 = 0.f, a6 = 0.f, a7 = 0.f;
            int j = beg;
            for (; j + 1 < end; j += 2) {
                int s0 = esrc[j], s1 = esrc[j + 1];
                U16 u0, u1;
                u0.u = z4[(long)s0 * 5 + lane];
                u1.u = z4[(long)s1 * 5 + lane];
                float2 p0 = __half22float2(u0.h[0]), p1 = __half22float2(u0.h[1]);
                float2 p2 = __half22float2(u0.h[2]), p3 = __half22float2(u0.h[3]);
                float2 q0 = __half22float2(u1.h[0]), q1 = __half22float2(u1.h[1]);
                float2 q2 = __half22float2(u1.h[2]), q3 = __half22float2(u1.h[3]);
                a0 += p0.x + q0.x; a1 += p0.y + q0.y;
                a2 += p1.x + q1.x; a3 += p1.y + q1.y;
                a4f += p2.x + q2.x; a5 += p2.y + q2.y;
                a6 += p3.x + q3.x; a7 += p3.y + q3.y;
            }
            if (j < end) {
                int s0 = esrc[j];
                U16 u0; u0.u = z4[(long)s0 * 5 + lane];
                float2 p0 = __half22float2(u0.h[0]), p1 = __half22float2(u0.h[1]);
                float2 p2 = __half22float2(u0.h[2]), p3 = __half22float2(u0.h[3]);
                a0 += p0.x; a1 += p0.y; a2 += p1.x; a3 += p1.y;
                a4f += p2.x; a5 += p2.y; a6 += p3.x; a7 += p3.y;
            }
            float nm = norm[n];
            const float4* b4 = reinterpret_cast<const float4*>(b2);
            float4 bb0 = b4[lane * 2], bb1 = b4[lane * 2 + 1];
            float4 o0, o1;
            o0.x = fmaf(a0, nm, bb0.x); o0.y = fmaf(a1, nm, bb0.y);
            o0.z = fmaf(a2, nm, bb0.z); o0.w = fmaf(a3, nm, bb0.w);
            o1.x = fmaf(a4f, nm, bb1.x); o1.y = fmaf(a5, nm, bb1.y);
            o1.z = fmaf(a6, nm, bb1.z); o1.w = fmaf(a7, nm, bb1.w);
            float4* out4 = reinterpret_cast<float4*>(out);
            out4[(long)n * 10 + lane * 2] = o0;
            out4[(long)n * 10 + lane * 2 + 1] = o1;
        }
    }
}

// ---------------- MFMA fused matmul ----------------

// Pre-pack W1 [128][128] f32 and W2 [128][40] f32 (padded to 48 cols) into fp16
// MFMA B-fragments: frag[(c*4+t)*64 + lane][j] = W[t*32 + (lane>>4)*8 + j][c*16 + (lane&15)]
__global__ void wprep_kernel(const float* __restrict__ W1, const float* __restrict__ W2,
                             __half* __restrict__ w1f, __half* __restrict__ w2f) {
    int tid = blockIdx.x * blockDim.x + threadIdx.x;
    if (tid < 2048) {                         // 8c * 4t * 64l
        int l = tid & 63;
        int t = (tid >> 6) & 3;
        int c = tid >> 8;
        int kb = t * 32 + (l >> 4) * 8, col = c * 16 + (l & 15);
        #pragma unroll
        for (int j = 0; j < 8; ++j)
            w1f[tid * 8 + j] = __float2half_rn(W1[(kb + j) * DHID + col]);
    } else if (tid < 2048 + 768) {            // 3c * 4t * 64l
        int id = tid - 2048;
        int l = id & 63;
        int t = (id >> 6) & 3;
        int c = id >> 8;
        int kb = t * 32 + (l >> 4) * 8, col = c * 16 + (l & 15);
        #pragma unroll
        for (int j = 0; j < 8; ++j)
            w2f[id * 8 + j] = (col < DOUT) ? __float2half_rn(W2[(kb + j) * DOUT + col])
                                           : __float2half_rn(0.f);
    }
}

// Fused: h = elu(aggh @ W1 + b1) staged in swizzled LDS (per-wave 16 rows),
//        z = fp16(norm * (h @ W2)). 64 rows/block, 4 waves.
__launch_bounds__(256, 2)
__global__ void mmfused_kernel(const __half* __restrict__ aggh,
                               const __half* __restrict__ w1f, const __half* __restrict__ w2f,
                               const float* __restrict__ b1, const float* __restrict__ norm,
                               __half* __restrict__ z, int N) {
    __shared__ uint4 w1l[2048];              // 32KB
    __shared__ uint4 w2l[768];               // 12KB
    __shared__ unsigned short hl[64 * 128];  // 16KB, XOR-swizzled
    int tid = threadIdx.x;
    const uint4* w1g = reinterpret_cast<const uint4*>(w1f);
    const uint4* w2g = reinterpret_cast<const uint4*>(w2f);
    for (int i = tid; i < 2048; i += 256) w1l[i] = w1g[i];
    for (int i = tid; i < 768; i += 256) w2l[i] = w2g[i];
    __syncthreads();

    int w = tid >> 6, l = tid & 63;
    int lr = l & 15, lg = l >> 4;
    float b1v[8];
    #pragma unroll
    for (int c = 0; c < 8; ++c) b1v[c] = b1[c * 16 + lr];

    int ntiles = (N + 63) >> 6;
    const uint4* ag = reinterpret_cast<const uint4*>(aggh);
    for (int tile = blockIdx.x; tile < ntiles; tile += gridDim.x) {
        int rb = tile << 6;
        // A-fragments straight from global (rows pre-normalized by gather1)
        int arow = rb + w * 16 + lr;
        int arc = min(arow, N - 1);
        F16X8 af[4];
        #pragma unroll
        for (int t = 0; t < 4; ++t) af[t].u = ag[(long)arc * 16 + t * 4 + lg];
        // ---- mm1: 8 col-tiles x 4 K-steps ----
        #pragma unroll
        for (int c = 0; c < 8; ++c) {
            f32x4 acc = {b1v[c], b1v[c], b1v[c], b1v[c]};
            #pragma unroll
            for (int t = 0; t < 4; ++t) {
                F16X8 bf; bf.u = w1l[(c * 4 + t) * 64 + l];
                acc = __builtin_amdgcn_mfma_f32_16x16x32_f16(af[t].f, bf.f, acc, 0, 0, 0);
            }
            int colb2 = (c * 16 + lr) * 2;
            #pragma unroll
            for (int i = 0; i < 4; ++i) {
                int rl = w * 16 + lg * 4 + i;
                HCV cv; cv.h = __float2half_rn(elu_f(acc[i]));
                int ba = (rl * 256 + colb2) ^ ((rl & 7) << 4);
                *reinterpret_cast<unsigned short*>(reinterpret_cast<char*>(hl) + ba) = cv.s;
            }
        }
        // ---- mm2: read own rows back (same-wave, no barrier), 3 col-tiles ----
        int rl2 = w * 16 + lr;
        int sw = (rl2 & 7) << 4;
        F16X8 hf[4];
        #pragma unroll
        for (int t = 0; t < 4; ++t) {
            int ba = (rl2 * 256 + (t * 32 + lg * 8) * 2) ^ sw;
            hf[t].u = *reinterpret_cast<const uint4*>(reinterpret_cast<const char*>(hl) + ba);
        }
        float nmv[4];
        #pragma unroll
        for (int i = 0; i < 4; ++i) {
            int r = rb + w * 16 + lg * 4 + i;
            nmv[i] = norm[min(r, N - 1)];
        }
        #pragma unroll
        for (int c = 0; c < 3; ++c) {
            f32x4 acc = {0.f, 0.f, 0.f, 0.f};
            #pragma unroll
            for (int t = 0; t < 4; ++t) {
                F16X8 bf; bf.u = w2l[(c * 4 + t) * 64 + l];
                acc = __builtin_amdgcn_mfma_f32_16x16x32_f16(hf[t].f, bf.f, acc, 0, 0, 0);
            }
            int col = c * 16 + lr;
            if (col < DOUT) {
                #pragma unroll
                for (int i = 0; i < 4; ++i) {
                    int r = rb + w * 16 + lg * 4 + i;
                    if (r < N) z[(long)r * DOUT + col] = __float2half_rn(acc[i] * nmv[i]);
                }
            }
        }
    }
}

// ---------------- fallback (f32 atomic path) ----------------

__global__ void scatter1_kernel(const float* __restrict__ feat, const int* __restrict__ src,
                                const int* __restrict__ dst, const float* __restrict__ norm,
                                float* __restrict__ agg, int E) {
    long T = (long)blockIdx.x * blockDim.x + threadIdx.x;
    int l4 = (int)(T & 31);
    long e = T >> 5;
    long estride = ((long)gridDim.x * blockDim.x) >> 5;
    for (; e < E; e += estride) {
        int s = src[e], d = dst[e];
        float ns = norm[s];
        float4 v = reinterpret_cast<const float4*>(feat)[(long)s * 32 + l4];
        float* o = agg + (long)d * DIN + l4 * 4;
        atomicAdd(o + 0, v.x * ns);
        atomicAdd(o + 1, v.y * ns);
        atomicAdd(o + 2, v.z * ns);
        atomicAdd(o + 3, v.w * ns);
    }
}

__global__ void scatter2_kernel(const float* __restrict__ z, const int* __restrict__ src,
                                const int* __restrict__ dst, float* __restrict__ out, int E) {
    long T = (long)blockIdx.x * blockDim.x + threadIdx.x;
    int l = (int)(T & 15);
    long e = T >> 4;
    long estride = ((long)gridDim.x * blockDim.x) >> 4;
    for (; e < E; e += estride) {
        if (l < 10) {
            int s = src[e], d = dst[e];
            float4 v = reinterpret_cast<const float4*>(z)[(long)s * 10 + l];
            float* o = out + (long)d * DOUT + l * 4;
            atomicAdd(o + 0, v.x);
            atomicAdd(o + 1, v.y);
            atomicAdd(o + 2, v.z);
            atomicAdd(o + 3, v.w);
        }
    }
}

__launch_bounds__(256, 2)
__global__ void mm1f_kernel(float* __restrict__ xh, const float* __restrict__ W1,
                            const float* __restrict__ b1, const float* __restrict__ norm,
                            int N) {
    __shared__ float Wl[DIN * DHID];
    __shared__ float Xl[32 * DIN];
    for (int i = threadIdx.x; i < DIN * DHID; i += 256) Wl[i] = W1[i];
    int cg = threadIdx.x & 31;
    int rg = threadIdx.x >> 5;
    int c0 = cg * 4;
    for (long r0 = (long)blockIdx.x * 32; r0 < N; r0 += (long)gridDim.x * 32) {
        __syncthreads();
        for (int i = threadIdx.x; i < 32 * 32; i += 256) {
            int rr = i >> 5;
            long row = r0 + rr;
            float4 v = make_float4(0.f, 0.f, 0.f, 0.f);
            if (row < N) {
                v = reinterpret_cast<const float4*>(xh)[row * 32 + (i & 31)];
                float nm = norm[row];
                v.x *= nm; v.y *= nm; v.z *= nm; v.w *= nm;
            }
            reinterpret_cast<float4*>(Xl)[i] = v;
        }
        __syncthreads();
        float acc[4][4];
        float bx = b1[c0], by = b1[c0 + 1], bz = b1[c0 + 2], bw = b1[c0 + 3];
        #pragma unroll
        for (int r = 0; r < 4; ++r) { acc[r][0] = bx; acc[r][1] = by; acc[r][2] = bz; acc[r][3] = bw; }
        for (int k = 0; k < DIN; k += 4) {
            float4 w0 = *reinterpret_cast<const float4*>(&Wl[(k + 0) * DHID + c0]);
            float4 w1 = *reinterpret_cast<const float4*>(&Wl[(k + 1) * DHID + c0]);
            float4 w2 = *reinterpret_cast<const float4*>(&Wl[(k + 2) * DHID + c0]);
            float4 w3 = *reinterpret_cast<const float4*>(&Wl[(k + 3) * DHID + c0]);
            #pragma unroll
            for (int r = 0; r < 4; ++r) {
                float4 x = *reinterpret_cast<const float4*>(&Xl[(rg * 4 + r) * DIN + k]);
                acc[r][0] = fmaf(x.x, w0.x, fmaf(x.y, w1.x, fmaf(x.z, w2.x, fmaf(x.w, w3.x, acc[r][0]))));
                acc[r][1] = fmaf(x.x, w0.y, fmaf(x.y, w1.y, fmaf(x.z, w2.y, fmaf(x.w, w3.y, acc[r][1]))));
                acc[r][2] = fmaf(x.x, w0.z, fmaf(x.y, w1.z, fmaf(x.z, w2.z, fmaf(x.w, w3.z, acc[r][2]))));
                acc[r][3] = fmaf(x.x, w0.w, fmaf(x.y, w1.w, fmaf(x.z, w2.w, fmaf(x.w, w3.w, acc[r][3]))));
            }
        }
        #pragma unroll
        for (int r = 0; r < 4; ++r) {
            long row = r0 + rg * 4 + r;
            if (row < N) {
                float4 o;
                o.x = elu_f(acc[r][0]); o.y = elu_f(acc[r][1]);
                o.z = elu_f(acc[r][2]); o.w = elu_f(acc[r][3]);
                *reinterpret_cast<float4*>(&xh[row * DIN + c0]) = o;
            }
        }
    }
}

__launch_bounds__(256, 2)
__global__ void mm2f_kernel(const float* __restrict__ h, const float* __restrict__ W2,
                            const float* __restrict__ norm, float* __restrict__ z, int N) {
    __shared__ float Wl[DHID * DOUT];
    __shared__ float Xl[64 * DIN];
    for (int i = threadIdx.x; i < DHID * DOUT; i += 256) Wl[i] = W2[i];
    int cg = threadIdx.x & 15;
    int rg = threadIdx.x >> 4;
    int c0 = cg * 4;
    for (long r0 = (long)blockIdx.x * 64; r0 < N; r0 += (long)gridDim.x * 64) {
        __syncthreads();
        for (int i = threadIdx.x; i < 64 * 32; i += 256) {
            int rr = i >> 5;
            long row = r0 + rr;
            float4 v = make_float4(0.f, 0.f, 0.f, 0.f);
            if (row < N) v = reinterpret_cast<const float4*>(h)[row * 32 + (i & 31)];
            reinterpret_cast<float4*>(Xl)[i] = v;
        }
        __syncthreads();
        if (c0 < DOUT) {
            float acc[4][4];
            #pragma unroll
            for (int r = 0; r < 4; ++r) { acc[r][0] = 0.f; acc[r][1] = 0.f; acc[r][2] = 0.f; acc[r][3] = 0.f; }
            for (int k = 0; k < DHID; k += 4) {
                float4 w0 = *reinterpret_cast<const float4*>(&Wl[(k + 0) * DOUT + c0]);
                float4 w1 = *reinterpret_cast<const float4*>(&Wl[(k + 1) * DOUT + c0]);
                float4 w2 = *reinterpret_cast<const float4*>(&Wl[(k + 2) * DOUT + c0]);
                float4 w3 = *reinterpret_cast<const float4*>(&Wl[(k + 3) * DOUT + c0]);
                #pragma unroll
                for (int r = 0; r < 4; ++r) {
                    float4 x = *reinterpret_cast<const float4*>(&Xl[(rg * 4 + r) * DIN + k]);
                    acc[r][0] = fmaf(x.x, w0.x, fmaf(x.y, w1.x, fmaf(x.z, w2.x, fmaf(x.w, w3.x, acc[r][0]))));
                    acc[r][1] = fmaf(x.x, w0.y, fmaf(x.y, w1.y, fmaf(x.z, w2.y, fmaf(x.w, w3.y, acc[r][1]))));
                    acc[r][2] = fmaf(x.x, w0.z, fmaf(x.y, w1.z, fmaf(x.z, w2.z, fmaf(x.w, w3.z, acc[r][2]))));
                    acc[r][3] = fmaf(x.x, w0.w, fmaf(x.y, w1.w, fmaf(x.z, w2.w, fmaf(x.w, w3.w, acc[r][3]))));
                }
            }
            #pragma unroll
            for (int r = 0; r < 4; ++r) {
                long row = r0 + rg * 4 + r;
                if (row < N) {
                    float nm = norm[row];
                    float4 o;
                    o.x = acc[r][0] * nm; o.y = acc[r][1] * nm;
                    o.z = acc[r][2] * nm; o.w = acc[r][3] * nm;
                    *reinterpret_cast<float4*>(&z[row * DOUT + c0]) = o;
                }
            }
        }
    }
}

__global__ void final_kernel(float* __restrict__ out, const float* __restrict__ norm,
                             const float* __restrict__ b2, int N) {
    long total = (long)N * DOUT;
    long stride = (long)gridDim.x * blockDim.x;
    for (long i = (long)blockIdx.x * blockDim.x + threadIdx.x; i < total; i += stride) {
        int n = (int)(i / DOUT), d = (int)(i % DOUT);
        out[i] = fmaf(out[i], norm[n], b2[d]);
    }
}

// ---------------- launch ----------------

static inline size_t al4k(size_t x) { return (x + 4095) & ~(size_t)4095; }

extern "C" void kernel_launch(void* const* d_in, const int* in_sizes, int n_in,
                              void* d_out, int out_size, void* d_ws, size_t ws_size,
                              hipStream_t stream) {
    const float* feat = (const float*)d_in[0];
    const int*   src  = (const int*)d_in[1];
    const int*   dst  = (const int*)d_in[2];
    const float* W1   = (const float*)d_in[3];
    const float* b1   = (const float*)d_in[4];
    const float* W2   = (const float*)d_in[5];
    const float* b2   = (const float*)d_in[6];
    int N = in_sizes[0] / DIN;
    int E = in_sizes[1];
    float* out = (float*)d_out;
    char* ws = (char*)d_ws;

    int NB = (N + BNODES - 1) >> BSHIFT;
    int cap = ((E / (NB > 0 ? NB : 1)) * 5 / 4 + 256 + 1) & ~1;

    size_t o_norm   = 0;
    size_t o_rowptr = o_norm   + al4k((size_t)N * 4);
    size_t o_bcur   = o_rowptr + al4k(((size_t)N + 1) * 4);
    size_t o_bbase  = o_bcur   + al4k((size_t)(NB + 1) * 4);
    size_t o_perm   = o_bbase  + al4k((size_t)(NB + 1) * 4);
    size_t o_esrc   = o_perm   + al4k((size_t)N * 4);
    size_t o_aggh   = o_esrc   + al4k((size_t)E * 4);       // packed bucketbuf aliases aggh
    size_t o_y      = o_aggh   + al4k((size_t)N * DIN * 2);
    size_t o_z      = o_y      + al4k((size_t)N * DIN * 2);
    size_t o_w1f    = o_z      + al4k((size_t)N * DOUT * 2);
    size_t o_w2f    = o_w1f    + al4k((size_t)16384 * 2);
    size_t need     = o_w2f    + al4k((size_t)6144 * 2);

    bool bb_fits = (size_t)NB * cap * 4 <= (size_t)N * DIN * 2;
    bool packs   = N <= (1 << 22);

    if (ws_size >= need && NB <= 256 && bb_fits && packs) {
        float*  norm   = (float*)(ws + o_norm);
        int*    rowptr = (int*)(ws + o_rowptr);
        int*    bcur   = (int*)(ws + o_bcur);
        int*    bbase  = (int*)(ws + o_bbase);
        int*    perm   = (int*)(ws + o_perm);
        int*    esrc   = (int*)(ws + o_esrc);
        __half* aggh   = (__half*)(ws + o_aggh);
        int*    bbuf   = (int*)(ws + o_aggh);
        __half* y      = (__half*)(ws + o_y);
        __half* z      = (__half*)(ws + o_z);
        __half* w1f    = (__half*)(ws + o_w1f);
        __half* w2f    = (__half*)(ws + o_w2f);

        hipMemsetAsync(bcur, 0, (size_t)(NB + 1) * 4, stream);

        wprep_kernel<<<11, 256, 0, stream>>>(W1, W2, w1f, w2f);
        int p1grid = (E + 8191) / 8192;
        pass1_bucket<<<p1grid, 256, 0, stream>>>(src, dst, E, NB, cap, bcur, bbuf);
        bucket_scan<<<1, 1, 0, stream>>>(bcur, bbase, NB);
        pass2_sort<<<NB, 256, 0, stream>>>(bbuf, bcur, bbase, N, NB, cap, norm, rowptr, esrc);
        perm_build<<<(N + 4095) / 4096, 256, 0, stream>>>(rowptr, perm, N);
        yconv_kernel<<<4096, 256, 0, stream>>>(feat, norm, y, N);

        gather1_kernel<<<(N * 16 + 255) / 256, 256, 0, stream>>>(y, rowptr, esrc, perm, norm, aggh, N);
        mmfused_kernel<<<512, 256, 0, stream>>>(aggh, w1f, w2f, b1, norm, z, N);
        gather2_kernel<<<(N * 8 + 255) / 256, 256, 0, stream>>>(z, rowptr, esrc, perm, norm, b2, out, N);
    } else {
        size_t f_norm = 0;
        size_t f_agg  = f_norm + al4k((size_t)N * 4);
        size_t f_z    = f_agg  + al4k((size_t)N * DIN * 4);
        float* norm = (float*)(ws + f_norm);
        float* agg  = (float*)(ws + f_agg);
        float* z    = (float*)(ws + f_z);
        int*   degi = (int*)(ws + f_norm);

        hipMemsetAsync(degi, 0, (size_t)N * 4, stream);
        hipMemsetAsync(agg, 0, (size_t)N * DIN * 4, stream);
        hipMemsetAsync(d_out, 0, (size_t)N * DOUT * 4, stream);

        degi_kernel<<<1024, 256, 0, stream>>>(dst, E, degi);
        norm_from_deg<<<(N + 255) / 256, 256, 0, stream>>>(degi, (float*)degi, N);
        scatter1_kernel<<<4096, 256, 0, stream>>>(feat, src, dst, norm, agg, E);
        mm1f_kernel<<<(N + 31) / 32, 256, 0, stream>>>(agg, W1, b1, norm, N);
        mm2f_kernel<<<(N + 63) / 64, 256, 0, stream>>>(agg, W2, norm, z, N);
        scatter2_kernel<<<4096, 256, 0, stream>>>(z, src, dst, out, E);
        final_kernel<<<4096, 256, 0, stream>>>(out, norm, b2, N);
    }
}